// Round 8
// baseline (192.574 us; speedup 1.0000x reference)
//
#include <hip/hip_runtime.h>

#define Bq 8
#define Sq 256
#define Hq 100
#define Pq 20
#define PPq 21
#define Fq 105
#define EPSq 1e-8f
#define NEGB -1e30f
#define IMG (128 * 136)   // padded bf16 operand image: 128 rows x 136 shorts (272 B)

typedef short bf16x8 __attribute__((ext_vector_type(8)));
typedef float f32x4 __attribute__((ext_vector_type(4)));

__device__ __forceinline__ unsigned fkey(float f) {
    unsigned b = __float_as_uint(f);
    return (b & 0x80000000u) ? ~b : (b | 0x80000000u);
}
__device__ __forceinline__ float funkey(unsigned k) {
    return __uint_as_float((k & 0x80000000u) ? (k ^ 0x80000000u) : ~k);
}
__device__ __forceinline__ unsigned short bf16rn(float f) {
    unsigned u = __float_as_uint(f);
    unsigned r = u + 0x7FFFu + ((u >> 16) & 1u);
    return (unsigned short)(r >> 16);
}
__device__ __forceinline__ unsigned mulpack(unsigned pair, float w0, float w1) {
    float f0 = __uint_as_float(pair << 16);
    float f1 = __uint_as_float(pair & 0xFFFF0000u);
    f0 *= w0; f1 *= w1;
    return ((unsigned)bf16rn(f0)) | (((unsigned)bf16rn(f1)) << 16);
}

// ---------------- k_prep: masks+lens, masked vm/vmT, bf16 images, 21 recip norms ----------
__global__ __launch_bounds__(256) void k_prep(
    const float* __restrict__ ctx_p, const int* __restrict__ mask_p,
    const float* __restrict__ ctx_h, const int* __restrict__ mask_h,
    const float* __restrict__ w_mp,
    float* __restrict__ vm, float* __restrict__ vmT,
    float* __restrict__ mf, float* __restrict__ wn,
    unsigned short* __restrict__ a16,   // [2 side][B][2 half][IMG]
    float* __restrict__ lens, int* __restrict__ lasts,
    unsigned* __restrict__ statinit) {  // 4*B*PP*S words to zero
    __shared__ float tileT[Hq * 257];
    __shared__ float w2T[Hq * 20];
    __shared__ float smf[256];
    __shared__ int ired[256];
    int side = blockIdx.x >> 3;
    int b = blockIdx.x & 7;
    int t = threadIdx.x;

    for (int idx = blockIdx.x * 256 + t; idx < 4 * Bq * PPq * Sq; idx += 16 * 256)
        statinit[idx] = 0u;

    const float* ctx = side ? ctx_h : ctx_p;
    const int* mask = side ? mask_h : mask_p;
    int mi = mask[b * Sq + t];
    smf[t] = (float)mi;
    ired[t] = mi;
    for (int idx = t; idx < Pq * Hq; idx += 256) {
        int p = idx / Hq, h = idx - p * Hq;
        float w = w_mp[idx];
        w2T[h * 20 + p] = w * w;
    }
    __syncthreads();
    for (int o = 128; o; o >>= 1) {
        if (t < o) ired[t] += ired[t + o];
        __syncthreads();
    }
    if (t == 0) {
        int l = ired[0];
        lens[side * Bq + b] = (float)l;
        lasts[side * Bq + b] = l > 0 ? l - 1 : 0;
    }

    unsigned short* abase = a16 + (size_t)(side * Bq + b) * 2 * IMG;
    // zero the pad region h in [100,136) of both halves
    {
        ushort4 z = {0, 0, 0, 0};
        for (int idx = t; idx < 2304; idx += 256) {
            int half = idx >= 1152;
            int rr = idx - half * 1152;
            int r = rr / 9, c = rr - r * 9;
            *(ushort4*)(abase + half * IMG + r * 136 + 100 + c * 4) = z;
        }
    }

    const float4* src = (const float4*)(ctx + (size_t)b * Sq * Hq);
    float4* vmo = (float4*)(vm + ((size_t)side * Bq + b) * Sq * Hq);
#pragma unroll
    for (int q = 0; q < 25; q++) {
        int F = t + 256 * q;
        int s = F / 25;
        int c = F - s * 25;
        float m = smf[s];
        float4 v4 = src[F];
        v4.x *= m; v4.y *= m; v4.z *= m; v4.w *= m;
        vmo[F] = v4;
        int h0 = c * 4;
        tileT[(h0 + 0) * 257 + s] = v4.x;
        tileT[(h0 + 1) * 257 + s] = v4.y;
        tileT[(h0 + 2) * 257 + s] = v4.z;
        tileT[(h0 + 3) * 257 + s] = v4.w;
        // bf16 padded-image write (8 B per thread per q)
        ushort4 o;
        o.x = bf16rn(v4.x); o.y = bf16rn(v4.y); o.z = bf16rn(v4.z); o.w = bf16rn(v4.w);
        *(ushort4*)(abase + (s >> 7) * IMG + (s & 127) * 136 + c * 4) = o;
    }
    __syncthreads();

    int s = t;
    float acc[PPq];
#pragma unroll
    for (int p = 0; p < PPq; p++) acc[p] = 0.f;
    float* vmTo = vmT + ((size_t)side * Bq + b) * Hq * Sq;
#pragma unroll 4
    for (int h = 0; h < Hq; h++) {
        float v = tileT[h * 257 + s];
        vmTo[h * Sq + s] = v;
        float e = v * v;
        acc[Pq] += e;
        const float4* wrow = (const float4*)(w2T + h * 20);
#pragma unroll
        for (int pq = 0; pq < 5; pq++) {
            float4 w4 = wrow[pq];
            acc[pq * 4 + 0] += w4.x * e;
            acc[pq * 4 + 1] += w4.y * e;
            acc[pq * 4 + 2] += w4.z * e;
            acc[pq * 4 + 3] += w4.w * e;
        }
    }
    float* wout = wn + ((size_t)side * Bq + b) * PPq * Sq;
#pragma unroll
    for (int p = 0; p < PPq; p++)
        wout[p * Sq + s] = 1.f / fmaxf(sqrtf(acc[p]), EPSq);
    mf[(size_t)side * Bq * Sq + b * Sq + s] = smf[s];
}

// ---------------- k_pw: blocks 0..63 = exact-f32 plain cosine (runs first);
//                  blocks 64..703 = bf16 MFMA weighted perspectives ------------------------
__global__ __launch_bounds__(256) void k_pw(
    const unsigned short* __restrict__ a16,
    const float* __restrict__ vmT,
    const float* __restrict__ wn, const float* __restrict__ mf,
    const float* __restrict__ w_mp, const float* __restrict__ lens,
    float* __restrict__ out, float* __restrict__ cosm, float* __restrict__ cosT,
    unsigned* __restrict__ rowmax, float* __restrict__ rowsum,
    unsigned* __restrict__ colmax, float* __restrict__ colsum) {
    __shared__ unsigned short As[IMG];   // [i][h] bf16, stride-136
    __shared__ unsigned short Bs[IMG];   // [j][h] bf16 of w^2*b
    __shared__ float w2s[144];
    int blk = blockIdx.x;
    int t = threadIdx.x;

    if (blk >= 64) {
        // ---------------- MFMA path ----------------
        int mblk = blk - 64;
        int b = mblk / 80;
        int rem = mblk - b * 80;
        int p = rem >> 2;
        int ih = (rem >> 1) & 1, jh = rem & 1;
        int i0 = ih * 128, j0 = jh * 128;

        if (t < 144) {
            float w = (t < Hq) ? w_mp[p * Hq + t] : 0.f;
            w2s[t] = w * w;
        }
        __syncthreads();

        // A: straight coalesced image copy (2176 x 16B chunks)
        {
            const uint4* sa = (const uint4*)(a16 + (size_t)(b * 2 + ih) * IMG);
            uint4* dA = (uint4*)As;
#pragma unroll
            for (int q = 0; q < 9; q++) {
                int idx = t + 256 * q;
                if (idx < 2176) dA[idx] = sa[idx];
            }
        }
        // B: coalesced chunk copy with on-the-fly w^2 multiply
        {
            const uint4* sb = (const uint4*)(a16 + (size_t)((Bq + b) * 2 + jh) * IMG);
            uint4* dB = (uint4*)Bs;
#pragma unroll
            for (int q = 0; q < 9; q++) {
                int idx = t + 256 * q;
                if (idx < 2176) {
                    int cc = idx - (idx / 17) * 17;   // chunk within row
                    int hb = cc * 8;
                    uint4 ch = sb[idx];
                    float4 wA = *(const float4*)(w2s + hb);
                    float4 wB = *(const float4*)(w2s + hb + 4);
                    uint4 o;
                    o.x = mulpack(ch.x, wA.x, wA.y);
                    o.y = mulpack(ch.y, wA.z, wA.w);
                    o.z = mulpack(ch.z, wB.x, wB.y);
                    o.w = mulpack(ch.w, wB.z, wB.w);
                    dB[idx] = o;
                }
            }
        }
        __syncthreads();

        int lane = t & 63;
        int wv = t >> 6;
        int wr = wv & 1, wc = wv >> 1;
        int lm = lane & 15, lq = lane >> 4;

        f32x4 acc[4][4];
#pragma unroll
        for (int tm = 0; tm < 4; tm++)
#pragma unroll
            for (int tn = 0; tn < 4; tn++) acc[tm][tn] = 0.f;

#pragma unroll
        for (int ks = 0; ks < 4; ks++) {
            bf16x8 af[4], bfr[4];
#pragma unroll
            for (int tm = 0; tm < 4; tm++)
                af[tm] = *(const bf16x8*)&As[(wr * 64 + tm * 16 + lm) * 136 + ks * 32 + lq * 8];
#pragma unroll
            for (int tn = 0; tn < 4; tn++)
                bfr[tn] = *(const bf16x8*)&Bs[(wc * 64 + tn * 16 + lm) * 136 + ks * 32 + lq * 8];
#pragma unroll
            for (int tm = 0; tm < 4; tm++)
#pragma unroll
                for (int tn = 0; tn < 4; tn++)
                    acc[tm][tn] = __builtin_amdgcn_mfma_f32_16x16x32_bf16(af[tm], bfr[tn], acc[tm][tn], 0, 0, 0);
        }

        // epilogue: one tm-group at a time (bounded register pressure)
        const float* wn0 = wn + ((size_t)b * PPq + p) * Sq;
        const float* wn1 = wn + ((size_t)(Bq + b) * PPq + p) * Sq;
        const float* mfp = mf + b * Sq;
        const float* mfh = mf + (size_t)Bq * Sq + b * Sq;
        size_t base = ((size_t)b * PPq + p) * Sq;
        float rn2v[4], mzh[4];
#pragma unroll
        for (int tn = 0; tn < 4; tn++) {
            int jj = j0 + wc * 64 + tn * 16 + lm;
            rn2v[tn] = wn1[jj];
            mzh[tn] = mfh[jj] > 0.5f ? 0.f : NEGB;
        }
        float cmax[4] = {NEGB, NEGB, NEGB, NEGB};
        float csum[4] = {0.f, 0.f, 0.f, 0.f};
#pragma unroll
        for (int tm = 0; tm < 4; tm++) {
            int ibase = i0 + wr * 64 + tm * 16 + lq * 4;
            float rn1v[4], mzp[4];
#pragma unroll
            for (int r2 = 0; r2 < 4; r2++) {
                rn1v[r2] = wn0[ibase + r2];
                mzp[r2] = mfp[ibase + r2] > 0.5f ? 0.f : NEGB;
            }
            float rmax[4] = {NEGB, NEGB, NEGB, NEGB};
            float rsum[4] = {0.f, 0.f, 0.f, 0.f};
#pragma unroll
            for (int tn = 0; tn < 4; tn++)
#pragma unroll
                for (int r2 = 0; r2 < 4; r2++) {
                    float v = acc[tm][tn][r2] * rn1v[r2] * rn2v[tn];
                    rmax[r2] = fmaxf(rmax[r2], v + mzh[tn]);
                    rsum[r2] += v;
                    cmax[tn] = fmaxf(cmax[tn], v + mzp[r2]);
                    csum[tn] += v;
                }
#pragma unroll
            for (int r2 = 0; r2 < 4; r2++)
#pragma unroll
                for (int o = 1; o < 16; o <<= 1) {
                    rmax[r2] = fmaxf(rmax[r2], __shfl_xor(rmax[r2], o, 64));
                    rsum[r2] += __shfl_xor(rsum[r2], o, 64);
                }
            if (lm == 0) {
#pragma unroll
                for (int r2 = 0; r2 < 4; r2++) {
                    atomicMax(rowmax + base + ibase + r2, fkey(rmax[r2]));
                    atomicAdd(rowsum + base + ibase + r2, rsum[r2]);
                }
            }
        }
#pragma unroll
        for (int tn = 0; tn < 4; tn++) {
#pragma unroll
            for (int o = 16; o < 64; o <<= 1) {
                cmax[tn] = fmaxf(cmax[tn], __shfl_xor(cmax[tn], o, 64));
                csum[tn] += __shfl_xor(csum[tn], o, 64);
            }
        }
        if (lq == 0) {
#pragma unroll
            for (int tn = 0; tn < 4; tn++) {
                int jj = j0 + wc * 64 + tn * 16 + lm;
                atomicMax(colmax + base + jj, fkey(cmax[tn]));
                atomicAdd(colsum + base + jj, csum[tn]);
            }
        }
        return;
    }

    // ---------------- exact-f32 plain cosine path (p == 20), blocks 0..63 ----------------
    float (*cbmax)[Sq] = (float (*)[Sq])As;            // alias MFMA LDS
    float (*cbsum)[Sq] = (float (*)[Sq])(As + 8192);
    int b = blk >> 3, it = blk & 7;
    int lane = t & 63;
    int wid = __builtin_amdgcn_readfirstlane(t >> 6);
    int i0 = it * 32 + wid * 8;

    const float* abase2 = vmT + (size_t)b * Hq * Sq;
    const float* bbase2 = vmT + (size_t)(Bq + b) * Hq * Sq;

    float4 acc[8];
#pragma unroll
    for (int k = 0; k < 8; k++) acc[k] = make_float4(0.f, 0.f, 0.f, 0.f);

#pragma unroll 4
    for (int h = 0; h < Hq; h++) {
        float4 bq = ((const float4*)(bbase2 + h * Sq))[lane];
        const float4* ap = (const float4*)(abase2 + h * Sq + i0);
        float4 a0 = ap[0], a1 = ap[1];
        float av[8] = {a0.x, a0.y, a0.z, a0.w, a1.x, a1.y, a1.z, a1.w};
#pragma unroll
        for (int k = 0; k < 8; k++) {
            acc[k].x += av[k] * bq.x; acc[k].y += av[k] * bq.y;
            acc[k].z += av[k] * bq.z; acc[k].w += av[k] * bq.w;
        }
    }

    const float* wn0 = wn + ((size_t)b * PPq + Pq) * Sq;
    const float* wn1 = wn + ((size_t)(Bq + b) * PPq + Pq) * Sq;
    float4 rn2 = ((const float4*)wn1)[lane];
    float4 mh4 = ((const float4*)(mf + (size_t)Bq * Sq + b * Sq))[lane];
    float invLh = 1.f / fmaxf(lens[Bq + b], EPSq);

    float cmax[4] = {NEGB, NEGB, NEGB, NEGB};
    float csum[4] = {0.f, 0.f, 0.f, 0.f};
#pragma unroll
    for (int k = 0; k < 8; k++) {
        float r1 = wn0[i0 + k];
        float4 v;
        v.x = acc[k].x * r1 * rn2.x;
        v.y = acc[k].y * r1 * rn2.y;
        v.z = acc[k].z * r1 * rn2.z;
        v.w = acc[k].w * r1 * rn2.w;
        float m0 = mh4.x > 0.5f ? v.x : NEGB;
        float m1 = mh4.y > 0.5f ? v.y : NEGB;
        float m2 = mh4.z > 0.5f ? v.z : NEGB;
        float m3 = mh4.w > 0.5f ? v.w : NEGB;
        float rmax = fmaxf(fmaxf(m0, m1), fmaxf(m2, m3));
        float rs = v.x + v.y + v.z + v.w;
        for (int o = 32; o; o >>= 1) {
            rmax = fmaxf(rmax, __shfl_xor(rmax, o, 64));
            rs += __shfl_xor(rs, o, 64);
        }
        if (lane == 0) {
            float* orow = out + ((size_t)(b * Sq + i0 + k)) * Fq;
            orow[0] = rmax;
            orow[1] = rs * invLh;
        }
        float mi = mf[b * Sq + i0 + k];
        if (mi > 0.5f) {
            cmax[0] = fmaxf(cmax[0], v.x); cmax[1] = fmaxf(cmax[1], v.y);
            cmax[2] = fmaxf(cmax[2], v.z); cmax[3] = fmaxf(cmax[3], v.w);
        }
        csum[0] += v.x; csum[1] += v.y; csum[2] += v.z; csum[3] += v.w;
        ((float4*)(cosm + (size_t)(b * Sq + i0 + k) * Sq))[lane] = v;
        int jb = 4 * lane;
        cosT[((size_t)b * Sq + jb + 0) * Sq + i0 + k] = v.x;
        cosT[((size_t)b * Sq + jb + 1) * Sq + i0 + k] = v.y;
        cosT[((size_t)b * Sq + jb + 2) * Sq + i0 + k] = v.z;
        cosT[((size_t)b * Sq + jb + 3) * Sq + i0 + k] = v.w;
    }
    ((float4*)&cbmax[wid][0])[lane] = make_float4(cmax[0], cmax[1], cmax[2], cmax[3]);
    ((float4*)&cbsum[wid][0])[lane] = make_float4(csum[0], csum[1], csum[2], csum[3]);
    __syncthreads();
    {
        int j = t;
        float mx = fmaxf(fmaxf(cbmax[0][j], cbmax[1][j]), fmaxf(cbmax[2][j], cbmax[3][j]));
        float sm = cbsum[0][j] + cbsum[1][j] + cbsum[2][j] + cbsum[3][j];
        size_t cidx = ((size_t)b * PPq + Pq) * Sq + j;
        atomicMax(colmax + cidx, fkey(mx));
        atomicAdd(colsum + cidx, sm);
    }
}

// ---------------- k_att: attention raw-sum & masked-max vectors (+ merged folds) ----------
__global__ __launch_bounds__(256) void k_att(
    const float* __restrict__ vm, const float* __restrict__ mf,
    const float* __restrict__ cosm, const float* __restrict__ cosT,
    const unsigned* __restrict__ rowmax, const float* __restrict__ rowsum,
    const unsigned* __restrict__ colmax, const float* __restrict__ colsum,
    const float* __restrict__ lens,
    float* __restrict__ out,
    float* __restrict__ attvT) {
    __shared__ float L[Sq * 8];
    __shared__ float bm[Sq];
    int blk = blockIdx.x;
    int t = threadIdx.x;

    if (blk < Bq * PPq) {            // col fold -> dir1 rows
        int bcf = blk / PPq, pcf = blk - bcf * PPq;
        float mx = funkey(colmax[(size_t)blk * Sq + t]);
        float sm = colsum[(size_t)blk * Sq + t];
        float invLp = 1.f / fmaxf(lens[bcf], EPSq);
        float* orow = out + (size_t)Bq * Sq * Fq + (size_t)(bcf * Sq + t) * Fq;
        if (pcf < Pq) { orow[23 + pcf] = mx; orow[43 + pcf] = sm * invLp; }
        else { orow[0] = mx; orow[1] = sm * invLp; }
    } else if (blk < 2 * Bq * PPq) { // row fold -> dir0 rows (p<20; p==20 by cos path)
        int rf = blk - Bq * PPq;
        int bcf = rf / PPq, pcf = rf - bcf * PPq;
        if (pcf < Pq) {
            float mx = funkey(rowmax[(size_t)(bcf * PPq + pcf) * Sq + t]);
            float sm = rowsum[(size_t)(bcf * PPq + pcf) * Sq + t];
            float invLh = 1.f / fmaxf(lens[Bq + bcf], EPSq);
            float* orow = out + (size_t)(bcf * Sq + t) * Fq;
            orow[23 + pcf] = mx; orow[43 + pcf] = sm * invLh;
        }
    }

    int d = blk >> 8;
    int rem = blk & 255;
    int b = rem >> 5, rt = rem & 31;
    int r0 = rt * 8;
    int h = t & 127, rh = t >> 7;

    const float* src = (d ? cosm : cosT) + (size_t)b * Sq * Sq;
#pragma unroll
    for (int q = 0; q < 2; q++) {
        int F = t + 256 * q;
        int k = F >> 1, c = F & 1;
        float4 v4 = *(const float4*)(src + (size_t)k * Sq + r0 + c * 4);
        *(float4*)(L + k * 8 + c * 4) = v4;
    }
    bm[t] = (mf[(size_t)(1 - d) * Bq * Sq + b * Sq + t] > 0.5f) ? 0.f : NEGB;
    __syncthreads();

    const float* vB = vm + (size_t)(1 - d) * Bq * Sq * Hq + (size_t)b * Sq * Hq + h;
    bool hv = (h < Hq);
    float am[4] = {0.f, 0.f, 0.f, 0.f};
    float ax[4] = {NEGB, NEGB, NEGB, NEGB};
#pragma unroll 16
    for (int k = 0; k < Sq; k++) {
        float v = hv ? vB[(size_t)k * Hq] : 0.f;
        float4 w = *(const float4*)(L + k * 8 + rh * 4);
        float bk = bm[k];
        float p0 = w.x * v, p1 = w.y * v, p2 = w.z * v, p3 = w.w * v;
        am[0] += p0; am[1] += p1; am[2] += p2; am[3] += p3;
        ax[0] = fmaxf(ax[0], p0 + bk); ax[1] = fmaxf(ax[1], p1 + bk);
        ax[2] = fmaxf(ax[2], p2 + bk); ax[3] = fmaxf(ax[3], p3 + bk);
    }
    if (hv) {
        int rb = r0 + rh * 4;
        float4 m4 = make_float4(am[0], am[1], am[2], am[3]);
        float4 x4 = make_float4(ax[0], ax[1], ax[2], ax[3]);
        *(float4*)(attvT + (((size_t)(d * 2 + 0) * Bq + b) * Hq + h) * Sq + rb) = m4;
        *(float4*)(attvT + (((size_t)(d * 2 + 1) * Bq + b) * Hq + h) * Sq + rb) = x4;
    }
}

// ---------------- k_final: full/att/maxatt _mpm — one wave per (m,dir,b,s-quarter) --------
__global__ __launch_bounds__(64) void k_final(
    const float* __restrict__ vm, const float* __restrict__ vmT,
    const int* __restrict__ lasts, const float* __restrict__ attvT,
    const float* __restrict__ w_full, const float* __restrict__ w_att,
    const float* __restrict__ w_maxatt,
    float* __restrict__ out) {
    __shared__ float w2T[Hq * 20];
    __shared__ float v2u[Hq];
    int blk = blockIdx.x;
    int m = blk >> 6;
    int rem = blk & 63;
    int dir = rem >> 5, b = (rem >> 2) & 7, sc = rem & 3;
    int t = threadIdx.x;
    const float* W = (m == 0) ? w_full : (m == 1) ? w_att : w_maxatt;
    for (int idx = t; idx < Pq * Hq; idx += 64) {
        int p = idx / Hq, h = idx - p * Hq;
        float w = W[idx];
        w2T[h * 20 + p] = w * w;
    }
    if (m == 0) {
        int lastO = dir ? lasts[b] : lasts[Bq + b];
        for (int hh = t; hh < Hq; hh += 64)
            v2u[hh] = vm[(size_t)(1 - dir) * Bq * Sq * Hq + ((size_t)b * Sq + lastO) * Hq + hh];
    }
    __syncthreads();

    int s = sc * 64 + t;
    const float* v1T = vmT + (size_t)(dir * Bq + b) * Hq * Sq;
    const float* v2T = attvT + ((size_t)(dir * 2 + (m == 2 ? 1 : 0)) * Bq + b) * Hq * Sq;

    float dotp[Pq], n1p[Pq], n2p[Pq];
#pragma unroll
    for (int p = 0; p < Pq; p++) { dotp[p] = 0.f; n1p[p] = 0.f; n2p[p] = 0.f; }
    float pd = 0.f, p1 = 0.f, p2 = 0.f;
#pragma unroll 2
    for (int h = 0; h < Hq; h++) {
        float v1 = v1T[h * Sq + s];
        float v2 = (m == 0) ? v2u[h] : v2T[h * Sq + s];
        float e1 = v1 * v2, e2 = v1 * v1, e3 = v2 * v2;
        pd += e1; p1 += e2; p2 += e3;
        const float4* wrow = (const float4*)(w2T + h * 20);
#pragma unroll
        for (int pq = 0; pq < 5; pq++) {
            float4 w4 = wrow[pq];
            dotp[pq * 4 + 0] += w4.x * e1; n1p[pq * 4 + 0] += w4.x * e2; n2p[pq * 4 + 0] += w4.x * e3;
            dotp[pq * 4 + 1] += w4.y * e1; n1p[pq * 4 + 1] += w4.y * e2; n2p[pq * 4 + 1] += w4.y * e3;
            dotp[pq * 4 + 2] += w4.z * e1; n1p[pq * 4 + 2] += w4.z * e2; n2p[pq * 4 + 2] += w4.z * e3;
            dotp[pq * 4 + 3] += w4.w * e1; n1p[pq * 4 + 3] += w4.w * e2; n2p[pq * 4 + 3] += w4.w * e3;
        }
    }
    int fbase = (m == 0) ? 2 : (m == 1) ? 63 : 84;
    float* orow = out + (size_t)dir * Bq * Sq * Fq + ((size_t)b * Sq + s) * Fq;
    orow[fbase] = pd / (fmaxf(sqrtf(p1), EPSq) * fmaxf(sqrtf(p2), EPSq));
#pragma unroll
    for (int p = 0; p < Pq; p++)
        orow[fbase + 1 + p] = dotp[p] / (fmaxf(sqrtf(n1p[p]), EPSq) * fmaxf(sqrtf(n2p[p]), EPSq));
}

extern "C" void kernel_launch(void* const* d_in, const int* in_sizes, int n_in,
                              void* d_out, int out_size, void* d_ws, size_t ws_size,
                              hipStream_t stream) {
    (void)in_sizes; (void)n_in; (void)out_size; (void)ws_size;
    const float* ctx_p    = (const float*)d_in[0];
    const int*   mask_p   = (const int*)d_in[1];
    const float* ctx_h    = (const float*)d_in[2];
    const int*   mask_h   = (const int*)d_in[3];
    const float* w_full   = (const float*)d_in[4];
    const float* w_maxpool= (const float*)d_in[5];
    const float* w_att    = (const float*)d_in[6];
    const float* w_maxatt = (const float*)d_in[7];
    float* out = (float*)d_out;
    float* ws = (float*)d_ws;

    const size_t BSH = (size_t)Bq * Sq * Hq;
    const size_t BS  = (size_t)Bq * Sq;
    const size_t BSS = (size_t)Bq * Sq * Sq;
    const size_t BPS = (size_t)Bq * PPq * Sq;

    float* vm     = ws;               ws += 2 * BSH;
    float* vmT    = ws;               ws += 2 * BSH;
    unsigned short* a16 = (unsigned short*)ws;  ws += 2 * Bq * IMG / 2 * 2;  // 2*8*2*IMG shorts
    float* mf     = ws;               ws += 2 * BS;
    float* wn     = ws;               ws += 2 * BPS;
    float* cosm   = ws;               ws += BSS;
    float* cosT   = ws;               ws += BSS;
    unsigned* rowmax = (unsigned*)ws; ws += BPS;
    float* rowsum = ws;               ws += BPS;
    unsigned* colmax = (unsigned*)ws; ws += BPS;
    float* colsum = ws;               ws += BPS;   // row/col stat bufs contiguous (one zero pass)
    float* attvT  = ws;               ws += 4 * BSH;
    float* lens   = ws;               ws += 16;
    int*   lasts  = (int*)ws;         ws += 16;

    k_prep<<<16, 256, 0, stream>>>(ctx_p, mask_p, ctx_h, mask_h, w_maxpool,
                                   vm, vmT, mf, wn, a16, lens, lasts, rowmax);
    k_pw<<<704, 256, 0, stream>>>(a16, vmT, wn, mf, w_maxpool, lens,
                                  out, cosm, cosT, rowmax, rowsum, colmax, colsum);
    k_att<<<512, 256, 0, stream>>>(vm, mf, cosm, cosT, rowmax, rowsum, colmax, colsum,
                                   lens, out, attvT);
    k_final<<<192, 64, 0, stream>>>(vm, vmT, lasts, attvT, w_full, w_att, w_maxatt, out);
}

// Round 10
// 150.118 us; speedup vs baseline: 1.2828x; 1.2828x over previous
//
#include <hip/hip_runtime.h>

#define Bq 8
#define Sq 256
#define Hq 100
#define Pq 20
#define PPq 21
#define Fq 105
#define EPSq 1e-8f
#define NEGB -1e30f
#define IMG (128 * 136)   // padded bf16 operand image: 128 rows x 136 shorts (272 B)

typedef short bf16x8 __attribute__((ext_vector_type(8)));
typedef float f32x4 __attribute__((ext_vector_type(4)));

__device__ __forceinline__ unsigned fkey(float f) {
    unsigned b = __float_as_uint(f);
    return (b & 0x80000000u) ? ~b : (b | 0x80000000u);
}
__device__ __forceinline__ float funkey(unsigned k) {
    return __uint_as_float((k & 0x80000000u) ? (k ^ 0x80000000u) : ~k);
}
__device__ __forceinline__ unsigned short bf16rn(float f) {
    unsigned u = __float_as_uint(f);
    unsigned r = u + 0x7FFFu + ((u >> 16) & 1u);
    return (unsigned short)(r >> 16);
}
__device__ __forceinline__ unsigned mulpack(unsigned pair, float w0, float w1) {
    float f0 = __uint_as_float(pair << 16);
    float f1 = __uint_as_float(pair & 0xFFFF0000u);
    f0 *= w0; f1 *= w1;
    return ((unsigned)bf16rn(f0)) | (((unsigned)bf16rn(f1)) << 16);
}

// ---------------- k_prep: masks+lens, masked vm/vmT, bf16 images, 21 recip norms ----------
__global__ __launch_bounds__(256) void k_prep(
    const float* __restrict__ ctx_p, const int* __restrict__ mask_p,
    const float* __restrict__ ctx_h, const int* __restrict__ mask_h,
    const float* __restrict__ w_mp,
    float* __restrict__ vm, float* __restrict__ vmT,
    float* __restrict__ mf, float* __restrict__ wn,
    unsigned short* __restrict__ a16,   // [2 side][B][2 half][IMG]
    float* __restrict__ lens, int* __restrict__ lasts,
    unsigned* __restrict__ statinit) {  // 4*B*PP*S words to zero
    __shared__ float tileT[Hq * 257];
    __shared__ float w2T[Hq * 20];
    __shared__ float smf[256];
    __shared__ int ired[256];
    int side = blockIdx.x >> 3;
    int b = blockIdx.x & 7;
    int t = threadIdx.x;

    for (int idx = blockIdx.x * 256 + t; idx < 4 * Bq * PPq * Sq; idx += 16 * 256)
        statinit[idx] = 0u;

    const float* ctx = side ? ctx_h : ctx_p;
    const int* mask = side ? mask_h : mask_p;
    int mi = mask[b * Sq + t];
    smf[t] = (float)mi;
    ired[t] = mi;
    for (int idx = t; idx < Pq * Hq; idx += 256) {
        int p = idx / Hq, h = idx - p * Hq;
        float w = w_mp[idx];
        w2T[h * 20 + p] = w * w;
    }
    __syncthreads();
    for (int o = 128; o; o >>= 1) {
        if (t < o) ired[t] += ired[t + o];
        __syncthreads();
    }
    if (t == 0) {
        int l = ired[0];
        lens[side * Bq + b] = (float)l;
        lasts[side * Bq + b] = l > 0 ? l - 1 : 0;
    }

    unsigned short* abase = a16 + (size_t)(side * Bq + b) * 2 * IMG;
    // zero the pad region h in [100,136) of both halves
    {
        ushort4 z = {0, 0, 0, 0};
        for (int idx = t; idx < 2304; idx += 256) {
            int half = idx >= 1152;
            int rr = idx - half * 1152;
            int r = rr / 9, c = rr - r * 9;
            *(ushort4*)(abase + half * IMG + r * 136 + 100 + c * 4) = z;
        }
    }

    const float4* src = (const float4*)(ctx + (size_t)b * Sq * Hq);
    float4* vmo = (float4*)(vm + ((size_t)side * Bq + b) * Sq * Hq);
#pragma unroll
    for (int q = 0; q < 25; q++) {
        int F = t + 256 * q;
        int s = F / 25;
        int c = F - s * 25;
        float m = smf[s];
        float4 v4 = src[F];
        v4.x *= m; v4.y *= m; v4.z *= m; v4.w *= m;
        vmo[F] = v4;
        int h0 = c * 4;
        tileT[(h0 + 0) * 257 + s] = v4.x;
        tileT[(h0 + 1) * 257 + s] = v4.y;
        tileT[(h0 + 2) * 257 + s] = v4.z;
        tileT[(h0 + 3) * 257 + s] = v4.w;
        // bf16 padded-image write (8 B per thread per q)
        ushort4 o;
        o.x = bf16rn(v4.x); o.y = bf16rn(v4.y); o.z = bf16rn(v4.z); o.w = bf16rn(v4.w);
        *(ushort4*)(abase + (s >> 7) * IMG + (s & 127) * 136 + c * 4) = o;
    }
    __syncthreads();

    int s = t;
    float acc[PPq];
#pragma unroll
    for (int p = 0; p < PPq; p++) acc[p] = 0.f;
    float* vmTo = vmT + ((size_t)side * Bq + b) * Hq * Sq;
#pragma unroll 4
    for (int h = 0; h < Hq; h++) {
        float v = tileT[h * 257 + s];
        vmTo[h * Sq + s] = v;
        float e = v * v;
        acc[Pq] += e;
        const float4* wrow = (const float4*)(w2T + h * 20);
#pragma unroll
        for (int pq = 0; pq < 5; pq++) {
            float4 w4 = wrow[pq];
            acc[pq * 4 + 0] += w4.x * e;
            acc[pq * 4 + 1] += w4.y * e;
            acc[pq * 4 + 2] += w4.z * e;
            acc[pq * 4 + 3] += w4.w * e;
        }
    }
    float* wout = wn + ((size_t)side * Bq + b) * PPq * Sq;
#pragma unroll
    for (int p = 0; p < PPq; p++)
        wout[p * Sq + s] = 1.f / fmaxf(sqrtf(acc[p]), EPSq);
    mf[(size_t)side * Bq * Sq + b * Sq + s] = smf[s];
}

// ---------------- k_pw: blocks 0..63 = exact-f32 plain cosine (runs first);
//                  blocks 64..703 = bf16 MFMA weighted perspectives ------------------------
__global__ __launch_bounds__(256) void k_pw(
    const unsigned short* __restrict__ a16,
    const float* __restrict__ vmT,
    const float* __restrict__ wn, const float* __restrict__ mf,
    const float* __restrict__ w_mp, const float* __restrict__ lens,
    float* __restrict__ out, float* __restrict__ cosm, float* __restrict__ cosT,
    unsigned* __restrict__ rowmax, float* __restrict__ rowsum,
    unsigned* __restrict__ colmax, float* __restrict__ colsum) {
    __shared__ unsigned short As[IMG];   // [i][h] bf16, stride-136
    __shared__ unsigned short Bs[IMG];   // [j][h] bf16 of w^2*b
    __shared__ float w2s[144];
    int blk = blockIdx.x;
    int t = threadIdx.x;

    if (blk >= 64) {
        // ---------------- MFMA path ----------------
        int mblk = blk - 64;
        int b = mblk / 80;
        int rem = mblk - b * 80;
        int p = rem >> 2;
        int ih = (rem >> 1) & 1, jh = rem & 1;
        int i0 = ih * 128, j0 = jh * 128;

        if (t < 144) {
            float w = (t < Hq) ? w_mp[p * Hq + t] : 0.f;
            w2s[t] = w * w;
        }
        __syncthreads();

        // A: straight coalesced image copy (2176 x 16B chunks)
        {
            const uint4* sa = (const uint4*)(a16 + (size_t)(b * 2 + ih) * IMG);
            uint4* dA = (uint4*)As;
#pragma unroll
            for (int q = 0; q < 9; q++) {
                int idx = t + 256 * q;
                if (idx < 2176) dA[idx] = sa[idx];
            }
        }
        // B: coalesced chunk copy with on-the-fly w^2 multiply
        {
            const uint4* sb = (const uint4*)(a16 + (size_t)((Bq + b) * 2 + jh) * IMG);
            uint4* dB = (uint4*)Bs;
#pragma unroll
            for (int q = 0; q < 9; q++) {
                int idx = t + 256 * q;
                if (idx < 2176) {
                    int cc = idx - (idx / 17) * 17;   // chunk within row
                    int hb = cc * 8;
                    uint4 ch = sb[idx];
                    float4 wA = *(const float4*)(w2s + hb);
                    float4 wB = *(const float4*)(w2s + hb + 4);
                    uint4 o;
                    o.x = mulpack(ch.x, wA.x, wA.y);
                    o.y = mulpack(ch.y, wA.z, wA.w);
                    o.z = mulpack(ch.z, wB.x, wB.y);
                    o.w = mulpack(ch.w, wB.z, wB.w);
                    dB[idx] = o;
                }
            }
        }
        __syncthreads();

        int lane = t & 63;
        int wv = t >> 6;
        int wr = wv & 1, wc = wv >> 1;
        int lm = lane & 15, lq = lane >> 4;

        f32x4 acc[4][4];
#pragma unroll
        for (int tm = 0; tm < 4; tm++)
#pragma unroll
            for (int tn = 0; tn < 4; tn++) acc[tm][tn] = 0.f;

#pragma unroll
        for (int ks = 0; ks < 4; ks++) {
            bf16x8 af[4], bfr[4];
#pragma unroll
            for (int tm = 0; tm < 4; tm++)
                af[tm] = *(const bf16x8*)&As[(wr * 64 + tm * 16 + lm) * 136 + ks * 32 + lq * 8];
#pragma unroll
            for (int tn = 0; tn < 4; tn++)
                bfr[tn] = *(const bf16x8*)&Bs[(wc * 64 + tn * 16 + lm) * 136 + ks * 32 + lq * 8];
#pragma unroll
            for (int tm = 0; tm < 4; tm++)
#pragma unroll
                for (int tn = 0; tn < 4; tn++)
                    acc[tm][tn] = __builtin_amdgcn_mfma_f32_16x16x32_bf16(af[tm], bfr[tn], acc[tm][tn], 0, 0, 0);
        }

        // epilogue: one tm-group at a time (bounded register pressure)
        const float* wn0 = wn + ((size_t)b * PPq + p) * Sq;
        const float* wn1 = wn + ((size_t)(Bq + b) * PPq + p) * Sq;
        const float* mfp = mf + b * Sq;
        const float* mfh = mf + (size_t)Bq * Sq + b * Sq;
        size_t base = ((size_t)b * PPq + p) * Sq;
        float rn2v[4], mzh[4];
#pragma unroll
        for (int tn = 0; tn < 4; tn++) {
            int jj = j0 + wc * 64 + tn * 16 + lm;
            rn2v[tn] = wn1[jj];
            mzh[tn] = mfh[jj] > 0.5f ? 0.f : NEGB;
        }
        float cmax[4] = {NEGB, NEGB, NEGB, NEGB};
        float csum[4] = {0.f, 0.f, 0.f, 0.f};
#pragma unroll
        for (int tm = 0; tm < 4; tm++) {
            int ibase = i0 + wr * 64 + tm * 16 + lq * 4;
            float rn1v[4], mzp[4];
#pragma unroll
            for (int r2 = 0; r2 < 4; r2++) {
                rn1v[r2] = wn0[ibase + r2];
                mzp[r2] = mfp[ibase + r2] > 0.5f ? 0.f : NEGB;
            }
            float rmax[4] = {NEGB, NEGB, NEGB, NEGB};
            float rsum[4] = {0.f, 0.f, 0.f, 0.f};
#pragma unroll
            for (int tn = 0; tn < 4; tn++)
#pragma unroll
                for (int r2 = 0; r2 < 4; r2++) {
                    float v = acc[tm][tn][r2] * rn1v[r2] * rn2v[tn];
                    rmax[r2] = fmaxf(rmax[r2], v + mzh[tn]);
                    rsum[r2] += v;
                    cmax[tn] = fmaxf(cmax[tn], v + mzp[r2]);
                    csum[tn] += v;
                }
#pragma unroll
            for (int r2 = 0; r2 < 4; r2++)
#pragma unroll
                for (int o = 1; o < 16; o <<= 1) {
                    rmax[r2] = fmaxf(rmax[r2], __shfl_xor(rmax[r2], o, 64));
                    rsum[r2] += __shfl_xor(rsum[r2], o, 64);
                }
            if (lm == 0) {
#pragma unroll
                for (int r2 = 0; r2 < 4; r2++) {
                    atomicMax(rowmax + base + ibase + r2, fkey(rmax[r2]));
                    atomicAdd(rowsum + base + ibase + r2, rsum[r2]);
                }
            }
        }
#pragma unroll
        for (int tn = 0; tn < 4; tn++) {
#pragma unroll
            for (int o = 16; o < 64; o <<= 1) {
                cmax[tn] = fmaxf(cmax[tn], __shfl_xor(cmax[tn], o, 64));
                csum[tn] += __shfl_xor(csum[tn], o, 64);
            }
        }
        if (lq == 0) {
#pragma unroll
            for (int tn = 0; tn < 4; tn++) {
                int jj = j0 + wc * 64 + tn * 16 + lm;
                atomicMax(colmax + base + jj, fkey(cmax[tn]));
                atomicAdd(colsum + base + jj, csum[tn]);
            }
        }
        return;
    }

    // ---------------- exact-f32 plain cosine path (p == 20), blocks 0..63 ----------------
    float (*cbmax)[Sq] = (float (*)[Sq])As;            // alias MFMA LDS
    float (*cbsum)[Sq] = (float (*)[Sq])(As + 8192);
    int b = blk >> 3, it = blk & 7;
    int lane = t & 63;
    int wid = __builtin_amdgcn_readfirstlane(t >> 6);
    int i0 = it * 32 + wid * 8;

    const float* abase2 = vmT + (size_t)b * Hq * Sq;
    const float* bbase2 = vmT + (size_t)(Bq + b) * Hq * Sq;

    float4 acc[8];
#pragma unroll
    for (int k = 0; k < 8; k++) acc[k] = make_float4(0.f, 0.f, 0.f, 0.f);

#pragma unroll 4
    for (int h = 0; h < Hq; h++) {
        float4 bq = ((const float4*)(bbase2 + h * Sq))[lane];
        const float4* ap = (const float4*)(abase2 + h * Sq + i0);
        float4 a0 = ap[0], a1 = ap[1];
        float av[8] = {a0.x, a0.y, a0.z, a0.w, a1.x, a1.y, a1.z, a1.w};
#pragma unroll
        for (int k = 0; k < 8; k++) {
            acc[k].x += av[k] * bq.x; acc[k].y += av[k] * bq.y;
            acc[k].z += av[k] * bq.z; acc[k].w += av[k] * bq.w;
        }
    }

    const float* wn0 = wn + ((size_t)b * PPq + Pq) * Sq;
    const float* wn1 = wn + ((size_t)(Bq + b) * PPq + Pq) * Sq;
    float4 rn2 = ((const float4*)wn1)[lane];
    float4 mh4 = ((const float4*)(mf + (size_t)Bq * Sq + b * Sq))[lane];
    float invLh = 1.f / fmaxf(lens[Bq + b], EPSq);

    float cmax[4] = {NEGB, NEGB, NEGB, NEGB};
    float csum[4] = {0.f, 0.f, 0.f, 0.f};
#pragma unroll
    for (int k = 0; k < 8; k++) {
        float r1 = wn0[i0 + k];
        float4 v;
        v.x = acc[k].x * r1 * rn2.x;
        v.y = acc[k].y * r1 * rn2.y;
        v.z = acc[k].z * r1 * rn2.z;
        v.w = acc[k].w * r1 * rn2.w;
        float m0 = mh4.x > 0.5f ? v.x : NEGB;
        float m1 = mh4.y > 0.5f ? v.y : NEGB;
        float m2 = mh4.z > 0.5f ? v.z : NEGB;
        float m3 = mh4.w > 0.5f ? v.w : NEGB;
        float rmax = fmaxf(fmaxf(m0, m1), fmaxf(m2, m3));
        float rs = v.x + v.y + v.z + v.w;
        for (int o = 32; o; o >>= 1) {
            rmax = fmaxf(rmax, __shfl_xor(rmax, o, 64));
            rs += __shfl_xor(rs, o, 64);
        }
        if (lane == 0) {
            float* orow = out + ((size_t)(b * Sq + i0 + k)) * Fq;
            orow[0] = rmax;
            orow[1] = rs * invLh;
        }
        float mi = mf[b * Sq + i0 + k];
        if (mi > 0.5f) {
            cmax[0] = fmaxf(cmax[0], v.x); cmax[1] = fmaxf(cmax[1], v.y);
            cmax[2] = fmaxf(cmax[2], v.z); cmax[3] = fmaxf(cmax[3], v.w);
        }
        csum[0] += v.x; csum[1] += v.y; csum[2] += v.z; csum[3] += v.w;
        ((float4*)(cosm + (size_t)(b * Sq + i0 + k) * Sq))[lane] = v;
        int jb = 4 * lane;
        cosT[((size_t)b * Sq + jb + 0) * Sq + i0 + k] = v.x;
        cosT[((size_t)b * Sq + jb + 1) * Sq + i0 + k] = v.y;
        cosT[((size_t)b * Sq + jb + 2) * Sq + i0 + k] = v.z;
        cosT[((size_t)b * Sq + jb + 3) * Sq + i0 + k] = v.w;
    }
    ((float4*)&cbmax[wid][0])[lane] = make_float4(cmax[0], cmax[1], cmax[2], cmax[3]);
    ((float4*)&cbsum[wid][0])[lane] = make_float4(csum[0], csum[1], csum[2], csum[3]);
    __syncthreads();
    {
        int j = t;
        float mx = fmaxf(fmaxf(cbmax[0][j], cbmax[1][j]), fmaxf(cbmax[2][j], cbmax[3][j]));
        float sm = cbsum[0][j] + cbsum[1][j] + cbsum[2][j] + cbsum[3][j];
        size_t cidx = ((size_t)b * PPq + Pq) * Sq + j;
        atomicMax(colmax + cidx, fkey(mx));
        atomicAdd(colsum + cidx, sm);
    }
}

// ---------------- k_att: attention raw-sum & masked-max vectors (+ merged folds) ----------
__global__ __launch_bounds__(256) void k_att(
    const float* __restrict__ vm, const float* __restrict__ mf,
    const float* __restrict__ cosm, const float* __restrict__ cosT,
    const unsigned* __restrict__ rowmax, const float* __restrict__ rowsum,
    const unsigned* __restrict__ colmax, const float* __restrict__ colsum,
    const float* __restrict__ lens,
    float* __restrict__ out,
    float* __restrict__ attvT) {
    __shared__ float L[Sq * 8];
    __shared__ float bm[Sq];
    int blk = blockIdx.x;
    int t = threadIdx.x;

    if (blk < Bq * PPq) {            // col fold -> dir1 rows
        int bcf = blk / PPq, pcf = blk - bcf * PPq;
        float mx = funkey(colmax[(size_t)blk * Sq + t]);
        float sm = colsum[(size_t)blk * Sq + t];
        float invLp = 1.f / fmaxf(lens[bcf], EPSq);
        float* orow = out + (size_t)Bq * Sq * Fq + (size_t)(bcf * Sq + t) * Fq;
        if (pcf < Pq) { orow[23 + pcf] = mx; orow[43 + pcf] = sm * invLp; }
        else { orow[0] = mx; orow[1] = sm * invLp; }
    } else if (blk < 2 * Bq * PPq) { // row fold -> dir0 rows (p<20; p==20 by cos path)
        int rf = blk - Bq * PPq;
        int bcf = rf / PPq, pcf = rf - bcf * PPq;
        if (pcf < Pq) {
            float mx = funkey(rowmax[(size_t)(bcf * PPq + pcf) * Sq + t]);
            float sm = rowsum[(size_t)(bcf * PPq + pcf) * Sq + t];
            float invLh = 1.f / fmaxf(lens[Bq + bcf], EPSq);
            float* orow = out + (size_t)(bcf * Sq + t) * Fq;
            orow[23 + pcf] = mx; orow[43 + pcf] = sm * invLh;
        }
    }

    int d = blk >> 8;
    int rem = blk & 255;
    int b = rem >> 5, rt = rem & 31;
    int r0 = rt * 8;
    int h = t & 127, rh = t >> 7;

    const float* src = (d ? cosm : cosT) + (size_t)b * Sq * Sq;
#pragma unroll
    for (int q = 0; q < 2; q++) {
        int F = t + 256 * q;
        int k = F >> 1, c = F & 1;
        float4 v4 = *(const float4*)(src + (size_t)k * Sq + r0 + c * 4);
        *(float4*)(L + k * 8 + c * 4) = v4;
    }
    bm[t] = (mf[(size_t)(1 - d) * Bq * Sq + b * Sq + t] > 0.5f) ? 0.f : NEGB;
    __syncthreads();

    const float* vB = vm + (size_t)(1 - d) * Bq * Sq * Hq + (size_t)b * Sq * Hq + h;
    bool hv = (h < Hq);
    float am[4] = {0.f, 0.f, 0.f, 0.f};
    float ax[4] = {NEGB, NEGB, NEGB, NEGB};
#pragma unroll 16
    for (int k = 0; k < Sq; k++) {
        float v = hv ? vB[(size_t)k * Hq] : 0.f;
        float4 w = *(const float4*)(L + k * 8 + rh * 4);
        float bk = bm[k];
        float p0 = w.x * v, p1 = w.y * v, p2 = w.z * v, p3 = w.w * v;
        am[0] += p0; am[1] += p1; am[2] += p2; am[3] += p3;
        ax[0] = fmaxf(ax[0], p0 + bk); ax[1] = fmaxf(ax[1], p1 + bk);
        ax[2] = fmaxf(ax[2], p2 + bk); ax[3] = fmaxf(ax[3], p3 + bk);
    }
    if (hv) {
        int rb = r0 + rh * 4;
        float4 m4 = make_float4(am[0], am[1], am[2], am[3]);
        float4 x4 = make_float4(ax[0], ax[1], ax[2], ax[3]);
        *(float4*)(attvT + (((size_t)(d * 2 + 0) * Bq + b) * Hq + h) * Sq + rb) = m4;
        *(float4*)(attvT + (((size_t)(d * 2 + 1) * Bq + b) * Hq + h) * Sq + rb) = x4;
    }
}

// ---------------- k_final: p-sliced — grid 960 = 3m*2dir*8b*2sc*10ps, 128 thr -------------
__global__ __launch_bounds__(128) void k_final(
    const float* __restrict__ vm, const float* __restrict__ vmT,
    const int* __restrict__ lasts, const float* __restrict__ attvT,
    const float* __restrict__ w_full, const float* __restrict__ w_att,
    const float* __restrict__ w_maxatt,
    float* __restrict__ out) {
    __shared__ float w2s[Hq * 2];    // [h][2] slice of w^2
    __shared__ float v2u[Hq];
    int blk = blockIdx.x;
    int m = blk / 320;               // 2dir * 8b * 2sc * 10ps = 320
    int rem = blk - m * 320;
    int dir = rem / 160; rem -= dir * 160;
    int b = rem / 20;    rem -= b * 20;
    int sc = rem / 10;
    int ps = rem - sc * 10;
    int t = threadIdx.x;
    const float* W = (m == 0) ? w_full : (m == 1) ? w_att : w_maxatt;
    for (int idx = t; idx < 2 * Hq; idx += 128) {
        int pp = idx / Hq, h = idx - pp * Hq;
        float w = W[(ps * 2 + pp) * Hq + h];
        w2s[h * 2 + pp] = w * w;
    }
    if (m == 0 && t < Hq) {
        int lastO = dir ? lasts[b] : lasts[Bq + b];
        v2u[t] = vm[(size_t)(1 - dir) * Bq * Sq * Hq + ((size_t)b * Sq + lastO) * Hq + t];
    }
    __syncthreads();

    int s = sc * 128 + t;
    const float* v1T = vmT + (size_t)(dir * Bq + b) * Hq * Sq + s;
    const float* v2T = attvT + ((size_t)(dir * 2 + (m == 2 ? 1 : 0)) * Bq + b) * Hq * Sq + s;

    float d0 = 0.f, a0 = 0.f, b0 = 0.f;
    float d1 = 0.f, a1 = 0.f, b1 = 0.f;
    float pd = 0.f, p1 = 0.f, p2 = 0.f;
#pragma unroll 4
    for (int h = 0; h < Hq; h++) {
        float v1 = v1T[h * Sq];
        float v2 = (m == 0) ? v2u[h] : v2T[h * Sq];
        float e1 = v1 * v2, e2 = v1 * v1, e3 = v2 * v2;
        float w0 = w2s[h * 2], w1 = w2s[h * 2 + 1];
        d0 += w0 * e1; a0 += w0 * e2; b0 += w0 * e3;
        d1 += w1 * e1; a1 += w1 * e2; b1 += w1 * e3;
        if (ps == 0) { pd += e1; p1 += e2; p2 += e3; }
    }
    int fbase = (m == 0) ? 2 : (m == 1) ? 63 : 84;
    float* orow = out + (size_t)dir * Bq * Sq * Fq + ((size_t)b * Sq + s) * Fq;
    if (ps == 0)
        orow[fbase] = pd / (fmaxf(sqrtf(p1), EPSq) * fmaxf(sqrtf(p2), EPSq));
    orow[fbase + 1 + ps * 2]     = d0 / (fmaxf(sqrtf(a0), EPSq) * fmaxf(sqrtf(b0), EPSq));
    orow[fbase + 1 + ps * 2 + 1] = d1 / (fmaxf(sqrtf(a1), EPSq) * fmaxf(sqrtf(b1), EPSq));
}

extern "C" void kernel_launch(void* const* d_in, const int* in_sizes, int n_in,
                              void* d_out, int out_size, void* d_ws, size_t ws_size,
                              hipStream_t stream) {
    (void)in_sizes; (void)n_in; (void)out_size; (void)ws_size;
    const float* ctx_p    = (const float*)d_in[0];
    const int*   mask_p   = (const int*)d_in[1];
    const float* ctx_h    = (const float*)d_in[2];
    const int*   mask_h   = (const int*)d_in[3];
    const float* w_full   = (const float*)d_in[4];
    const float* w_maxpool= (const float*)d_in[5];
    const float* w_att    = (const float*)d_in[6];
    const float* w_maxatt = (const float*)d_in[7];
    float* out = (float*)d_out;
    float* ws = (float*)d_ws;

    const size_t BSH = (size_t)Bq * Sq * Hq;
    const size_t BS  = (size_t)Bq * Sq;
    const size_t BSS = (size_t)Bq * Sq * Sq;
    const size_t BPS = (size_t)Bq * PPq * Sq;

    float* vm     = ws;               ws += 2 * BSH;
    float* vmT    = ws;               ws += 2 * BSH;
    unsigned short* a16 = (unsigned short*)ws;  ws += 2 * Bq * IMG / 2 * 2;  // 2*8*2*IMG shorts
    float* mf     = ws;               ws += 2 * BS;
    float* wn     = ws;               ws += 2 * BPS;
    float* cosm   = ws;               ws += BSS;
    float* cosT   = ws;               ws += BSS;
    unsigned* rowmax = (unsigned*)ws; ws += BPS;
    float* rowsum = ws;               ws += BPS;
    unsigned* colmax = (unsigned*)ws; ws += BPS;
    float* colsum = ws;               ws += BPS;   // row/col stat bufs contiguous (one zero pass)
    float* attvT  = ws;               ws += 4 * BSH;
    float* lens   = ws;               ws += 16;
    int*   lasts  = (int*)ws;         ws += 16;

    k_prep<<<16, 256, 0, stream>>>(ctx_p, mask_p, ctx_h, mask_h, w_maxpool,
                                   vm, vmT, mf, wn, a16, lens, lasts, rowmax);
    k_pw<<<704, 256, 0, stream>>>(a16, vmT, wn, mf, w_maxpool, lens,
                                  out, cosm, cosT, rowmax, rowsum, colmax, colsum);
    k_att<<<512, 256, 0, stream>>>(vm, mf, cosm, cosT, rowmax, rowsum, colmax, colsum,
                                   lens, out, attvT);
    k_final<<<960, 128, 0, stream>>>(vm, vmT, lasts, attvT, w_full, w_att, w_maxatt, out);
}

// Round 11
// 135.511 us; speedup vs baseline: 1.4211x; 1.1078x over previous
//
#include <hip/hip_runtime.h>

#define Bq 8
#define Sq 256
#define Hq 100
#define Pq 20
#define PPq 21
#define Fq 105
#define EPSq 1e-8f
#define NEGB -1e30f
#define IMG (128 * 136)   // padded bf16 operand image: 128 rows x 136 shorts (272 B)

typedef short bf16x8 __attribute__((ext_vector_type(8)));
typedef float f32x4 __attribute__((ext_vector_type(4)));

__device__ __forceinline__ unsigned fkey(float f) {
    unsigned b = __float_as_uint(f);
    return (b & 0x80000000u) ? ~b : (b | 0x80000000u);
}
__device__ __forceinline__ float funkey(unsigned k) {
    return __uint_as_float((k & 0x80000000u) ? (k ^ 0x80000000u) : ~k);
}
__device__ __forceinline__ unsigned short bf16rn(float f) {
    unsigned u = __float_as_uint(f);
    unsigned r = u + 0x7FFFu + ((u >> 16) & 1u);
    return (unsigned short)(r >> 16);
}
__device__ __forceinline__ unsigned mulpack(unsigned pair, float w0, float w1) {
    float f0 = __uint_as_float(pair << 16);
    float f1 = __uint_as_float(pair & 0xFFFF0000u);
    f0 *= w0; f1 *= w1;
    return ((unsigned)bf16rn(f0)) | (((unsigned)bf16rn(f1)) << 16);
}

// ---------------- k_prep: 64 blocks = (side, b, 64-token quarter) -------------------------
__global__ __launch_bounds__(256) void k_prep(
    const float* __restrict__ ctx_p, const int* __restrict__ mask_p,
    const float* __restrict__ ctx_h, const int* __restrict__ mask_h,
    const float* __restrict__ w_mp,
    float* __restrict__ vm, float* __restrict__ vmT,
    float* __restrict__ mf, float* __restrict__ wn,
    unsigned short* __restrict__ a16,   // [2 side][B][2 half][IMG]
    float* __restrict__ lens, int* __restrict__ lasts,
    unsigned* __restrict__ statinit) {  // 4*B*PP*S words to zero
    __shared__ float tileT[Hq * 65];    // [h][s_local], stride-65 pad
    __shared__ float w2T[Hq * 20];      // [h][p]
    __shared__ float redp[PPq * 4 * 64];// [p][hq][sl]
    __shared__ float smf[64];
    __shared__ int ired[256];
    int blk = blockIdx.x;
    int side = blk >> 5;
    int b = (blk >> 2) & 7;
    int sq = blk & 3;
    int s0 = sq * 64;
    int t = threadIdx.x;

    for (int idx = blk * 256 + t; idx < 4 * Bq * PPq * Sq; idx += 64 * 256)
        statinit[idx] = 0u;

    const float* ctx = side ? ctx_h : ctx_p;
    const int* mask = side ? mask_h : mask_p;
    ired[t] = mask[b * Sq + t];
    if (t < 64) smf[t] = (float)mask[b * Sq + s0 + t];
    for (int idx = t; idx < Pq * Hq; idx += 256) {
        int p = idx / Hq, h = idx - p * Hq;
        float w = w_mp[idx];
        w2T[h * 20 + p] = w * w;
    }
    __syncthreads();
    if (sq == 0) {                      // block-uniform branch: syncthreads legal
        for (int o = 128; o; o >>= 1) {
            if (t < o) ired[t] += ired[t + o];
            __syncthreads();
        }
        if (t == 0) {
            int l = ired[0];
            lens[side * Bq + b] = (float)l;
            lasts[side * Bq + b] = l > 0 ? l - 1 : 0;
        }
    }

    unsigned short* abase = a16 + (size_t)(side * Bq + b) * 2 * IMG;
    // zero pad region h in [100,136) for this block's 64 rows
    {
        ushort4 z = {0, 0, 0, 0};
        for (int idx = t; idx < 576; idx += 256) {
            int r = idx / 9, c = idx - r * 9;
            int g = s0 + r;
            *(ushort4*)(abase + (g >> 7) * IMG + (g & 127) * 136 + 100 + c * 4) = z;
        }
    }

    const float4* src = (const float4*)(ctx + ((size_t)b * Sq + s0) * Hq);
    float4* vmo = (float4*)(vm + ((size_t)side * Bq + b) * Sq * Hq + (size_t)s0 * Hq);
#pragma unroll
    for (int q = 0; q < 7; q++) {
        int F = t + 256 * q;
        if (F < 1600) {
            int s = F / 25, c = F - s * 25;
            float m = smf[s];
            float4 v4 = src[F];
            v4.x *= m; v4.y *= m; v4.z *= m; v4.w *= m;
            vmo[F] = v4;
            int h0 = c * 4;
            tileT[(h0 + 0) * 65 + s] = v4.x;
            tileT[(h0 + 1) * 65 + s] = v4.y;
            tileT[(h0 + 2) * 65 + s] = v4.z;
            tileT[(h0 + 3) * 65 + s] = v4.w;
            int g = s0 + s;
            ushort4 o;
            o.x = bf16rn(v4.x); o.y = bf16rn(v4.y); o.z = bf16rn(v4.z); o.w = bf16rn(v4.w);
            *(ushort4*)(abase + (g >> 7) * IMG + (g & 127) * 136 + c * 4) = o;
        }
    }
    __syncthreads();

    int sl = t & 63, hq = t >> 6;
    float acc[PPq];
#pragma unroll
    for (int p = 0; p < PPq; p++) acc[p] = 0.f;
    float* vmTo = vmT + ((size_t)side * Bq + b) * Hq * Sq + s0;
    int hbeg = hq * 25;
#pragma unroll 5
    for (int h = hbeg; h < hbeg + 25; h++) {
        float v = tileT[h * 65 + sl];
        vmTo[(size_t)h * Sq + sl] = v;
        float e = v * v;
        acc[Pq] += e;
        const float4* wrow = (const float4*)(w2T + h * 20);
#pragma unroll
        for (int pq = 0; pq < 5; pq++) {
            float4 w4 = wrow[pq];
            acc[pq * 4 + 0] += w4.x * e;
            acc[pq * 4 + 1] += w4.y * e;
            acc[pq * 4 + 2] += w4.z * e;
            acc[pq * 4 + 3] += w4.w * e;
        }
    }
#pragma unroll
    for (int p = 0; p < PPq; p++)
        redp[(p * 4 + hq) * 64 + sl] = acc[p];
    __syncthreads();

    float* wout = wn + ((size_t)side * Bq + b) * PPq * Sq + s0;
    for (int idx = t; idx < PPq * 64; idx += 256) {
        int p = idx >> 6, s2 = idx & 63;
        float ssum = redp[(p * 4 + 0) * 64 + s2] + redp[(p * 4 + 1) * 64 + s2] +
                     redp[(p * 4 + 2) * 64 + s2] + redp[(p * 4 + 3) * 64 + s2];
        wout[p * Sq + s2] = 1.f / fmaxf(sqrtf(ssum), EPSq);
    }
    if (t < 64) mf[(size_t)side * Bq * Sq + b * Sq + s0 + t] = smf[t];
}

// ---------------- k_pw: blocks 0..63 = exact-f32 plain cosine (runs first);
//                  blocks 64..703 = bf16 MFMA weighted perspectives ------------------------
__global__ __launch_bounds__(256) void k_pw(
    const unsigned short* __restrict__ a16,
    const float* __restrict__ vmT,
    const float* __restrict__ wn, const float* __restrict__ mf,
    const float* __restrict__ w_mp, const float* __restrict__ lens,
    float* __restrict__ out, float* __restrict__ cosm, float* __restrict__ cosT,
    unsigned* __restrict__ rowmax, float* __restrict__ rowsum,
    unsigned* __restrict__ colmax, float* __restrict__ colsum) {
    __shared__ unsigned short As[IMG];   // [i][h] bf16, stride-136
    __shared__ unsigned short Bs[IMG];   // [j][h] bf16 of w^2*b
    __shared__ float w2s[144];
    int blk = blockIdx.x;
    int t = threadIdx.x;

    if (blk >= 64) {
        // ---------------- MFMA path ----------------
        int mblk = blk - 64;
        int b = mblk / 80;
        int rem = mblk - b * 80;
        int p = rem >> 2;
        int ih = (rem >> 1) & 1, jh = rem & 1;
        int i0 = ih * 128, j0 = jh * 128;

        if (t < 144) {
            float w = (t < Hq) ? w_mp[p * Hq + t] : 0.f;
            w2s[t] = w * w;
        }
        __syncthreads();

        {
            const uint4* sa = (const uint4*)(a16 + (size_t)(b * 2 + ih) * IMG);
            uint4* dA = (uint4*)As;
#pragma unroll
            for (int q = 0; q < 9; q++) {
                int idx = t + 256 * q;
                if (idx < 2176) dA[idx] = sa[idx];
            }
        }
        {
            const uint4* sb = (const uint4*)(a16 + (size_t)((Bq + b) * 2 + jh) * IMG);
            uint4* dB = (uint4*)Bs;
#pragma unroll
            for (int q = 0; q < 9; q++) {
                int idx = t + 256 * q;
                if (idx < 2176) {
                    int cc = idx - (idx / 17) * 17;
                    int hb = cc * 8;
                    uint4 ch = sb[idx];
                    float4 wA = *(const float4*)(w2s + hb);
                    float4 wB = *(const float4*)(w2s + hb + 4);
                    uint4 o;
                    o.x = mulpack(ch.x, wA.x, wA.y);
                    o.y = mulpack(ch.y, wA.z, wA.w);
                    o.z = mulpack(ch.z, wB.x, wB.y);
                    o.w = mulpack(ch.w, wB.z, wB.w);
                    dB[idx] = o;
                }
            }
        }
        __syncthreads();

        int lane = t & 63;
        int wv = t >> 6;
        int wr = wv & 1, wc = wv >> 1;
        int lm = lane & 15, lq = lane >> 4;

        f32x4 acc[4][4];
#pragma unroll
        for (int tm = 0; tm < 4; tm++)
#pragma unroll
            for (int tn = 0; tn < 4; tn++) acc[tm][tn] = 0.f;

#pragma unroll
        for (int ks = 0; ks < 4; ks++) {
            bf16x8 af[4], bfr[4];
#pragma unroll
            for (int tm = 0; tm < 4; tm++)
                af[tm] = *(const bf16x8*)&As[(wr * 64 + tm * 16 + lm) * 136 + ks * 32 + lq * 8];
#pragma unroll
            for (int tn = 0; tn < 4; tn++)
                bfr[tn] = *(const bf16x8*)&Bs[(wc * 64 + tn * 16 + lm) * 136 + ks * 32 + lq * 8];
#pragma unroll
            for (int tm = 0; tm < 4; tm++)
#pragma unroll
                for (int tn = 0; tn < 4; tn++)
                    acc[tm][tn] = __builtin_amdgcn_mfma_f32_16x16x32_bf16(af[tm], bfr[tn], acc[tm][tn], 0, 0, 0);
        }

        const float* wn0 = wn + ((size_t)b * PPq + p) * Sq;
        const float* wn1 = wn + ((size_t)(Bq + b) * PPq + p) * Sq;
        const float* mfp = mf + b * Sq;
        const float* mfh = mf + (size_t)Bq * Sq + b * Sq;
        size_t base = ((size_t)b * PPq + p) * Sq;
        float rn2v[4], mzh[4];
#pragma unroll
        for (int tn = 0; tn < 4; tn++) {
            int jj = j0 + wc * 64 + tn * 16 + lm;
            rn2v[tn] = wn1[jj];
            mzh[tn] = mfh[jj] > 0.5f ? 0.f : NEGB;
        }
        float cmax[4] = {NEGB, NEGB, NEGB, NEGB};
        float csum[4] = {0.f, 0.f, 0.f, 0.f};
#pragma unroll
        for (int tm = 0; tm < 4; tm++) {
            int ibase = i0 + wr * 64 + tm * 16 + lq * 4;
            float rn1v[4], mzp[4];
#pragma unroll
            for (int r2 = 0; r2 < 4; r2++) {
                rn1v[r2] = wn0[ibase + r2];
                mzp[r2] = mfp[ibase + r2] > 0.5f ? 0.f : NEGB;
            }
            float rmax[4] = {NEGB, NEGB, NEGB, NEGB};
            float rsum[4] = {0.f, 0.f, 0.f, 0.f};
#pragma unroll
            for (int tn = 0; tn < 4; tn++)
#pragma unroll
                for (int r2 = 0; r2 < 4; r2++) {
                    float v = acc[tm][tn][r2] * rn1v[r2] * rn2v[tn];
                    rmax[r2] = fmaxf(rmax[r2], v + mzh[tn]);
                    rsum[r2] += v;
                    cmax[tn] = fmaxf(cmax[tn], v + mzp[r2]);
                    csum[tn] += v;
                }
#pragma unroll
            for (int r2 = 0; r2 < 4; r2++)
#pragma unroll
                for (int o = 1; o < 16; o <<= 1) {
                    rmax[r2] = fmaxf(rmax[r2], __shfl_xor(rmax[r2], o, 64));
                    rsum[r2] += __shfl_xor(rsum[r2], o, 64);
                }
            if (lm == 0) {
#pragma unroll
                for (int r2 = 0; r2 < 4; r2++) {
                    atomicMax(rowmax + base + ibase + r2, fkey(rmax[r2]));
                    atomicAdd(rowsum + base + ibase + r2, rsum[r2]);
                }
            }
        }
#pragma unroll
        for (int tn = 0; tn < 4; tn++) {
#pragma unroll
            for (int o = 16; o < 64; o <<= 1) {
                cmax[tn] = fmaxf(cmax[tn], __shfl_xor(cmax[tn], o, 64));
                csum[tn] += __shfl_xor(csum[tn], o, 64);
            }
        }
        if (lq == 0) {
#pragma unroll
            for (int tn = 0; tn < 4; tn++) {
                int jj = j0 + wc * 64 + tn * 16 + lm;
                atomicMax(colmax + base + jj, fkey(cmax[tn]));
                atomicAdd(colsum + base + jj, csum[tn]);
            }
        }
        return;
    }

    // ---------------- exact-f32 plain cosine path (p == 20), blocks 0..63 ----------------
    float (*cbmax)[Sq] = (float (*)[Sq])As;
    float (*cbsum)[Sq] = (float (*)[Sq])(As + 8192);
    int b = blk >> 3, it = blk & 7;
    int lane = t & 63;
    int wid = __builtin_amdgcn_readfirstlane(t >> 6);
    int i0 = it * 32 + wid * 8;

    const float* abase2 = vmT + (size_t)b * Hq * Sq;
    const float* bbase2 = vmT + (size_t)(Bq + b) * Hq * Sq;

    float4 acc[8];
#pragma unroll
    for (int k = 0; k < 8; k++) acc[k] = make_float4(0.f, 0.f, 0.f, 0.f);

#pragma unroll 4
    for (int h = 0; h < Hq; h++) {
        float4 bq = ((const float4*)(bbase2 + h * Sq))[lane];
        const float4* ap = (const float4*)(abase2 + h * Sq + i0);
        float4 a0 = ap[0], a1 = ap[1];
        float av[8] = {a0.x, a0.y, a0.z, a0.w, a1.x, a1.y, a1.z, a1.w};
#pragma unroll
        for (int k = 0; k < 8; k++) {
            acc[k].x += av[k] * bq.x; acc[k].y += av[k] * bq.y;
            acc[k].z += av[k] * bq.z; acc[k].w += av[k] * bq.w;
        }
    }

    const float* wn0 = wn + ((size_t)b * PPq + Pq) * Sq;
    const float* wn1 = wn + ((size_t)(Bq + b) * PPq + Pq) * Sq;
    float4 rn2 = ((const float4*)wn1)[lane];
    float4 mh4 = ((const float4*)(mf + (size_t)Bq * Sq + b * Sq))[lane];
    float invLh = 1.f / fmaxf(lens[Bq + b], EPSq);

    float cmax[4] = {NEGB, NEGB, NEGB, NEGB};
    float csum[4] = {0.f, 0.f, 0.f, 0.f};
#pragma unroll
    for (int k = 0; k < 8; k++) {
        float r1 = wn0[i0 + k];
        float4 v;
        v.x = acc[k].x * r1 * rn2.x;
        v.y = acc[k].y * r1 * rn2.y;
        v.z = acc[k].z * r1 * rn2.z;
        v.w = acc[k].w * r1 * rn2.w;
        float m0 = mh4.x > 0.5f ? v.x : NEGB;
        float m1 = mh4.y > 0.5f ? v.y : NEGB;
        float m2 = mh4.z > 0.5f ? v.z : NEGB;
        float m3 = mh4.w > 0.5f ? v.w : NEGB;
        float rmax = fmaxf(fmaxf(m0, m1), fmaxf(m2, m3));
        float rs = v.x + v.y + v.z + v.w;
        for (int o = 32; o; o >>= 1) {
            rmax = fmaxf(rmax, __shfl_xor(rmax, o, 64));
            rs += __shfl_xor(rs, o, 64);
        }
        if (lane == 0) {
            float* orow = out + ((size_t)(b * Sq + i0 + k)) * Fq;
            orow[0] = rmax;
            orow[1] = rs * invLh;
        }
        float mi = mf[b * Sq + i0 + k];
        if (mi > 0.5f) {
            cmax[0] = fmaxf(cmax[0], v.x); cmax[1] = fmaxf(cmax[1], v.y);
            cmax[2] = fmaxf(cmax[2], v.z); cmax[3] = fmaxf(cmax[3], v.w);
        }
        csum[0] += v.x; csum[1] += v.y; csum[2] += v.z; csum[3] += v.w;
        ((float4*)(cosm + (size_t)(b * Sq + i0 + k) * Sq))[lane] = v;
        int jb = 4 * lane;
        cosT[((size_t)b * Sq + jb + 0) * Sq + i0 + k] = v.x;
        cosT[((size_t)b * Sq + jb + 1) * Sq + i0 + k] = v.y;
        cosT[((size_t)b * Sq + jb + 2) * Sq + i0 + k] = v.z;
        cosT[((size_t)b * Sq + jb + 3) * Sq + i0 + k] = v.w;
    }
    ((float4*)&cbmax[wid][0])[lane] = make_float4(cmax[0], cmax[1], cmax[2], cmax[3]);
    ((float4*)&cbsum[wid][0])[lane] = make_float4(csum[0], csum[1], csum[2], csum[3]);
    __syncthreads();
    {
        int j = t;
        float mx = fmaxf(fmaxf(cbmax[0][j], cbmax[1][j]), fmaxf(cbmax[2][j], cbmax[3][j]));
        float sm = cbsum[0][j] + cbsum[1][j] + cbsum[2][j] + cbsum[3][j];
        size_t cidx = ((size_t)b * PPq + Pq) * Sq + j;
        atomicMax(colmax + cidx, fkey(mx));
        atomicAdd(colsum + cidx, sm);
    }
}

// ---------------- k_att: 512 threads, k-loop split in half, LDS merge ---------------------
__global__ __launch_bounds__(512) void k_att(
    const float* __restrict__ vm, const float* __restrict__ mf,
    const float* __restrict__ cosm, const float* __restrict__ cosT,
    const unsigned* __restrict__ rowmax, const float* __restrict__ rowsum,
    const unsigned* __restrict__ colmax, const float* __restrict__ colsum,
    const float* __restrict__ lens,
    float* __restrict__ out,
    float* __restrict__ attvT) {
    __shared__ float L[Sq * 8];
    __shared__ float bm[Sq];
    __shared__ float pam[2][4][256];
    __shared__ float pax[2][4][256];
    int blk = blockIdx.x;
    int t = threadIdx.x;

    if (t < 256) {
        if (blk < Bq * PPq) {            // col fold -> dir1 rows
            int bcf = blk / PPq, pcf = blk - bcf * PPq;
            float mx = funkey(colmax[(size_t)blk * Sq + t]);
            float sm = colsum[(size_t)blk * Sq + t];
            float invLp = 1.f / fmaxf(lens[bcf], EPSq);
            float* orow = out + (size_t)Bq * Sq * Fq + (size_t)(bcf * Sq + t) * Fq;
            if (pcf < Pq) { orow[23 + pcf] = mx; orow[43 + pcf] = sm * invLp; }
            else { orow[0] = mx; orow[1] = sm * invLp; }
        } else if (blk < 2 * Bq * PPq) { // row fold -> dir0 rows (p<20; p==20 by cos path)
            int rf = blk - Bq * PPq;
            int bcf = rf / PPq, pcf = rf - bcf * PPq;
            if (pcf < Pq) {
                float mx = funkey(rowmax[(size_t)(bcf * PPq + pcf) * Sq + t]);
                float sm = rowsum[(size_t)(bcf * PPq + pcf) * Sq + t];
                float invLh = 1.f / fmaxf(lens[Bq + bcf], EPSq);
                float* orow = out + (size_t)(bcf * Sq + t) * Fq;
                orow[23 + pcf] = mx; orow[43 + pcf] = sm * invLh;
            }
        }
        bm[t] = (mf[(size_t)(1 - (blk >> 8)) * Bq * Sq + ((blk & 255) >> 5) * Sq + t] > 0.5f) ? 0.f : NEGB;
    }

    int d = blk >> 8;
    int rem = blk & 255;
    int b = rem >> 5, rt = rem & 31;
    int r0 = rt * 8;
    int h = t & 127, rh = (t >> 7) & 1, kh = t >> 8;

    const float* src = (d ? cosm : cosT) + (size_t)b * Sq * Sq;
    {
        int k = t >> 1, c = t & 1;       // 512 threads = 512 float4 = full L
        float4 v4 = *(const float4*)(src + (size_t)k * Sq + r0 + c * 4);
        *(float4*)(L + k * 8 + c * 4) = v4;
    }
    __syncthreads();

    const float* vB = vm + (size_t)(1 - d) * Bq * Sq * Hq + (size_t)b * Sq * Hq + h;
    bool hv = (h < Hq);
    float am[4] = {0.f, 0.f, 0.f, 0.f};
    float ax[4] = {NEGB, NEGB, NEGB, NEGB};
    int k0 = kh * 128;
#pragma unroll 16
    for (int kk = 0; kk < 128; kk++) {
        int k = k0 + kk;
        float v = hv ? vB[(size_t)k * Hq] : 0.f;
        float4 w = *(const float4*)(L + k * 8 + rh * 4);
        float bk = bm[k];
        float p0 = w.x * v, p1 = w.y * v, p2 = w.z * v, p3 = w.w * v;
        am[0] += p0; am[1] += p1; am[2] += p2; am[3] += p3;
        ax[0] = fmaxf(ax[0], p0 + bk); ax[1] = fmaxf(ax[1], p1 + bk);
        ax[2] = fmaxf(ax[2], p2 + bk); ax[3] = fmaxf(ax[3], p3 + bk);
    }
    int hr = t & 255;
#pragma unroll
    for (int r = 0; r < 4; r++) { pam[kh][r][hr] = am[r]; pax[kh][r][hr] = ax[r]; }
    __syncthreads();
    if (t < 256 && hv) {
        int rb = r0 + rh * 4;
        float4 m4, x4;
        m4.x = pam[0][0][t] + pam[1][0][t]; x4.x = fmaxf(pax[0][0][t], pax[1][0][t]);
        m4.y = pam[0][1][t] + pam[1][1][t]; x4.y = fmaxf(pax[0][1][t], pax[1][1][t]);
        m4.z = pam[0][2][t] + pam[1][2][t]; x4.z = fmaxf(pax[0][2][t], pax[1][2][t]);
        m4.w = pam[0][3][t] + pam[1][3][t]; x4.w = fmaxf(pax[0][3][t], pax[1][3][t]);
        *(float4*)(attvT + (((size_t)(d * 2 + 0) * Bq + b) * Hq + h) * Sq + rb) = m4;
        *(float4*)(attvT + (((size_t)(d * 2 + 1) * Bq + b) * Hq + h) * Sq + rb) = x4;
    }
}

// ---------------- k_final: p-sliced — grid 960 = 3m*2dir*8b*2sc*10ps, 128 thr -------------
__global__ __launch_bounds__(128) void k_final(
    const float* __restrict__ vm, const float* __restrict__ vmT,
    const int* __restrict__ lasts, const float* __restrict__ attvT,
    const float* __restrict__ w_full, const float* __restrict__ w_att,
    const float* __restrict__ w_maxatt,
    float* __restrict__ out) {
    __shared__ float w2s[Hq * 2];    // [h][2] slice of w^2
    __shared__ float v2u[Hq];
    int blk = blockIdx.x;
    int m = blk / 320;               // 2dir * 8b * 2sc * 10ps = 320
    int rem = blk - m * 320;
    int dir = rem / 160; rem -= dir * 160;
    int b = rem / 20;    rem -= b * 20;
    int sc = rem / 10;
    int ps = rem - sc * 10;
    int t = threadIdx.x;
    const float* W = (m == 0) ? w_full : (m == 1) ? w_att : w_maxatt;
    for (int idx = t; idx < 2 * Hq; idx += 128) {
        int pp = idx / Hq, h = idx - pp * Hq;
        float w = W[(ps * 2 + pp) * Hq + h];
        w2s[h * 2 + pp] = w * w;
    }
    if (m == 0 && t < Hq) {
        int lastO = dir ? lasts[b] : lasts[Bq + b];
        v2u[t] = vm[(size_t)(1 - dir) * Bq * Sq * Hq + ((size_t)b * Sq + lastO) * Hq + t];
    }
    __syncthreads();

    int s = sc * 128 + t;
    const float* v1T = vmT + (size_t)(dir * Bq + b) * Hq * Sq + s;
    const float* v2T = attvT + ((size_t)(dir * 2 + (m == 2 ? 1 : 0)) * Bq + b) * Hq * Sq + s;

    float d0 = 0.f, a0 = 0.f, b0 = 0.f;
    float d1 = 0.f, a1 = 0.f, b1 = 0.f;
    float pd = 0.f, p1 = 0.f, p2 = 0.f;
#pragma unroll 4
    for (int h = 0; h < Hq; h++) {
        float v1 = v1T[h * Sq];
        float v2 = (m == 0) ? v2u[h] : v2T[h * Sq];
        float e1 = v1 * v2, e2 = v1 * v1, e3 = v2 * v2;
        float w0 = w2s[h * 2], w1 = w2s[h * 2 + 1];
        d0 += w0 * e1; a0 += w0 * e2; b0 += w0 * e3;
        d1 += w1 * e1; a1 += w1 * e2; b1 += w1 * e3;
        if (ps == 0) { pd += e1; p1 += e2; p2 += e3; }
    }
    int fbase = (m == 0) ? 2 : (m == 1) ? 63 : 84;
    float* orow = out + (size_t)dir * Bq * Sq * Fq + ((size_t)b * Sq + s) * Fq;
    if (ps == 0)
        orow[fbase] = pd / (fmaxf(sqrtf(p1), EPSq) * fmaxf(sqrtf(p2), EPSq));
    orow[fbase + 1 + ps * 2]     = d0 / (fmaxf(sqrtf(a0), EPSq) * fmaxf(sqrtf(b0), EPSq));
    orow[fbase + 1 + ps * 2 + 1] = d1 / (fmaxf(sqrtf(a1), EPSq) * fmaxf(sqrtf(b1), EPSq));
}

extern "C" void kernel_launch(void* const* d_in, const int* in_sizes, int n_in,
                              void* d_out, int out_size, void* d_ws, size_t ws_size,
                              hipStream_t stream) {
    (void)in_sizes; (void)n_in; (void)out_size; (void)ws_size;
    const float* ctx_p    = (const float*)d_in[0];
    const int*   mask_p   = (const int*)d_in[1];
    const float* ctx_h    = (const float*)d_in[2];
    const int*   mask_h   = (const int*)d_in[3];
    const float* w_full   = (const float*)d_in[4];
    const float* w_maxpool= (const float*)d_in[5];
    const float* w_att    = (const float*)d_in[6];
    const float* w_maxatt = (const float*)d_in[7];
    float* out = (float*)d_out;
    float* ws = (float*)d_ws;

    const size_t BSH = (size_t)Bq * Sq * Hq;
    const size_t BS  = (size_t)Bq * Sq;
    const size_t BSS = (size_t)Bq * Sq * Sq;
    const size_t BPS = (size_t)Bq * PPq * Sq;

    float* vm     = ws;               ws += 2 * BSH;
    float* vmT    = ws;               ws += 2 * BSH;
    unsigned short* a16 = (unsigned short*)ws;  ws += 2 * Bq * IMG / 2 * 2;  // 2*8*2*IMG shorts
    float* mf     = ws;               ws += 2 * BS;
    float* wn     = ws;               ws += 2 * BPS;
    float* cosm   = ws;               ws += BSS;
    float* cosT   = ws;               ws += BSS;
    unsigned* rowmax = (unsigned*)ws; ws += BPS;
    float* rowsum = ws;               ws += BPS;
    unsigned* colmax = (unsigned*)ws; ws += BPS;
    float* colsum = ws;               ws += BPS;   // row/col stat bufs contiguous (one zero pass)
    float* attvT  = ws;               ws += 4 * BSH;
    float* lens   = ws;               ws += 16;
    int*   lasts  = (int*)ws;         ws += 16;

    k_prep<<<64, 256, 0, stream>>>(ctx_p, mask_p, ctx_h, mask_h, w_maxpool,
                                   vm, vmT, mf, wn, a16, lens, lasts, rowmax);
    k_pw<<<704, 256, 0, stream>>>(a16, vmT, wn, mf, w_maxpool, lens,
                                  out, cosm, cosT, rowmax, rowsum, colmax, colsum);
    k_att<<<512, 512, 0, stream>>>(vm, mf, cosm, cosT, rowmax, rowsum, colmax, colsum,
                                   lens, out, attvT);
    k_final<<<960, 128, 0, stream>>>(vm, vmT, lasts, attvT, w_full, w_att, w_maxatt, out);
}

// Round 12
// 135.318 us; speedup vs baseline: 1.4231x; 1.0014x over previous
//
#include <hip/hip_runtime.h>

#define Bq 8
#define Sq 256
#define Hq 100
#define Pq 20
#define PPq 21
#define Fq 105
#define EPSq 1e-8f
#define NEGB -1e30f
#define IMG (128 * 136)   // padded bf16 operand image: 128 rows x 136 shorts (272 B)

typedef short bf16x8 __attribute__((ext_vector_type(8)));
typedef float f32x4 __attribute__((ext_vector_type(4)));

__device__ __forceinline__ unsigned fkey(float f) {
    unsigned b = __float_as_uint(f);
    return (b & 0x80000000u) ? ~b : (b | 0x80000000u);
}
__device__ __forceinline__ float funkey(unsigned k) {
    return __uint_as_float((k & 0x80000000u) ? (k ^ 0x80000000u) : ~k);
}
__device__ __forceinline__ unsigned short bf16rn(float f) {
    unsigned u = __float_as_uint(f);
    unsigned r = u + 0x7FFFu + ((u >> 16) & 1u);
    return (unsigned short)(r >> 16);
}
__device__ __forceinline__ unsigned mulpack(unsigned pair, float w0, float w1) {
    float f0 = __uint_as_float(pair << 16);
    float f1 = __uint_as_float(pair & 0xFFFF0000u);
    f0 *= w0; f1 *= w1;
    return ((unsigned)bf16rn(f0)) | (((unsigned)bf16rn(f1)) << 16);
}

// ---------------- k_prep: 64 blocks = (side, b, 64-token quarter) -------------------------
__global__ __launch_bounds__(256) void k_prep(
    const float* __restrict__ ctx_p, const int* __restrict__ mask_p,
    const float* __restrict__ ctx_h, const int* __restrict__ mask_h,
    const float* __restrict__ w_mp,
    float* __restrict__ vm, float* __restrict__ vmT,
    float* __restrict__ mf, float* __restrict__ wn,
    unsigned short* __restrict__ a16,   // [2 side][B][2 half][IMG]
    float* __restrict__ lens, int* __restrict__ lasts,
    unsigned* __restrict__ statinit) {  // 4*B*PP*S words to zero
    __shared__ float tileT[Hq * 65];    // [h][s_local], stride-65 pad
    __shared__ float w2T[Hq * 20];      // [h][p]
    __shared__ float redp[PPq * 4 * 64];// [p][hq][sl]
    __shared__ float smf[64];
    __shared__ int ired[256];
    int blk = blockIdx.x;
    int side = blk >> 5;
    int b = (blk >> 2) & 7;
    int sq = blk & 3;
    int s0 = sq * 64;
    int t = threadIdx.x;

    for (int idx = blk * 256 + t; idx < 4 * Bq * PPq * Sq; idx += 64 * 256)
        statinit[idx] = 0u;

    const float* ctx = side ? ctx_h : ctx_p;
    const int* mask = side ? mask_h : mask_p;
    ired[t] = mask[b * Sq + t];
    if (t < 64) smf[t] = (float)mask[b * Sq + s0 + t];
    for (int idx = t; idx < Pq * Hq; idx += 256) {
        int p = idx / Hq, h = idx - p * Hq;
        float w = w_mp[idx];
        w2T[h * 20 + p] = w * w;
    }
    __syncthreads();
    if (sq == 0) {                      // block-uniform branch: syncthreads legal
        for (int o = 128; o; o >>= 1) {
            if (t < o) ired[t] += ired[t + o];
            __syncthreads();
        }
        if (t == 0) {
            int l = ired[0];
            lens[side * Bq + b] = (float)l;
            lasts[side * Bq + b] = l > 0 ? l - 1 : 0;
        }
    }

    unsigned short* abase = a16 + (size_t)(side * Bq + b) * 2 * IMG;
    // zero pad region h in [100,136) for this block's 64 rows
    {
        ushort4 z = {0, 0, 0, 0};
        for (int idx = t; idx < 576; idx += 256) {
            int r = idx / 9, c = idx - r * 9;
            int g = s0 + r;
            *(ushort4*)(abase + (g >> 7) * IMG + (g & 127) * 136 + 100 + c * 4) = z;
        }
    }

    const float4* src = (const float4*)(ctx + ((size_t)b * Sq + s0) * Hq);
    float4* vmo = (float4*)(vm + ((size_t)side * Bq + b) * Sq * Hq + (size_t)s0 * Hq);
#pragma unroll
    for (int q = 0; q < 7; q++) {
        int F = t + 256 * q;
        if (F < 1600) {
            int s = F / 25, c = F - s * 25;
            float m = smf[s];
            float4 v4 = src[F];
            v4.x *= m; v4.y *= m; v4.z *= m; v4.w *= m;
            vmo[F] = v4;
            int h0 = c * 4;
            tileT[(h0 + 0) * 65 + s] = v4.x;
            tileT[(h0 + 1) * 65 + s] = v4.y;
            tileT[(h0 + 2) * 65 + s] = v4.z;
            tileT[(h0 + 3) * 65 + s] = v4.w;
            int g = s0 + s;
            ushort4 o;
            o.x = bf16rn(v4.x); o.y = bf16rn(v4.y); o.z = bf16rn(v4.z); o.w = bf16rn(v4.w);
            *(ushort4*)(abase + (g >> 7) * IMG + (g & 127) * 136 + c * 4) = o;
        }
    }
    __syncthreads();

    int sl = t & 63, hq = t >> 6;
    float acc[PPq];
#pragma unroll
    for (int p = 0; p < PPq; p++) acc[p] = 0.f;
    float* vmTo = vmT + ((size_t)side * Bq + b) * Hq * Sq + s0;
    int hbeg = hq * 25;
#pragma unroll 5
    for (int h = hbeg; h < hbeg + 25; h++) {
        float v = tileT[h * 65 + sl];
        vmTo[(size_t)h * Sq + sl] = v;
        float e = v * v;
        acc[Pq] += e;
        const float4* wrow = (const float4*)(w2T + h * 20);
#pragma unroll
        for (int pq = 0; pq < 5; pq++) {
            float4 w4 = wrow[pq];
            acc[pq * 4 + 0] += w4.x * e;
            acc[pq * 4 + 1] += w4.y * e;
            acc[pq * 4 + 2] += w4.z * e;
            acc[pq * 4 + 3] += w4.w * e;
        }
    }
#pragma unroll
    for (int p = 0; p < PPq; p++)
        redp[(p * 4 + hq) * 64 + sl] = acc[p];
    __syncthreads();

    float* wout = wn + ((size_t)side * Bq + b) * PPq * Sq + s0;
    for (int idx = t; idx < PPq * 64; idx += 256) {
        int p = idx >> 6, s2 = idx & 63;
        float ssum = redp[(p * 4 + 0) * 64 + s2] + redp[(p * 4 + 1) * 64 + s2] +
                     redp[(p * 4 + 2) * 64 + s2] + redp[(p * 4 + 3) * 64 + s2];
        wout[p * Sq + s2] = 1.f / fmaxf(sqrtf(ssum), EPSq);
    }
    if (t < 64) mf[(size_t)side * Bq * Sq + b * Sq + s0 + t] = smf[t];
}

// ---------------- k_pw: blocks 0..63 = exact-f32 plain cosine (runs first);
//                  blocks 64..703 = bf16 MFMA weighted perspectives, K-split 36 KB LDS -----
__global__ __launch_bounds__(256) void k_pw(
    const unsigned short* __restrict__ a16,
    const float* __restrict__ vmT,
    const float* __restrict__ wn, const float* __restrict__ mf,
    const float* __restrict__ w_mp, const float* __restrict__ lens,
    float* __restrict__ out, float* __restrict__ cosm, float* __restrict__ cosT,
    unsigned* __restrict__ rowmax, float* __restrict__ rowsum,
    unsigned* __restrict__ colmax, float* __restrict__ colsum) {
    __shared__ unsigned short As[128 * 72];   // [i][h-chunk] bf16, stride-72 (18 KB)
    __shared__ unsigned short Bs[128 * 72];   // [j][h-chunk] bf16 of w^2*b (18 KB)
    __shared__ float w2s[144];
    int blk = blockIdx.x;
    int t = threadIdx.x;

    if (blk >= 64) {
        // ---------------- MFMA path ----------------
        int mblk = blk - 64;
        int b = mblk / 80;
        int rem = mblk - b * 80;
        int p = rem >> 2;
        int ih = (rem >> 1) & 1, jh = rem & 1;
        int i0 = ih * 128, j0 = jh * 128;

        if (t < 144) {
            float w = (t < Hq) ? w_mp[p * Hq + t] : 0.f;
            w2s[t] = w * w;
        }
        __syncthreads();

        const uint4* sa = (const uint4*)(a16 + (size_t)(b * 2 + ih) * IMG);
        const uint4* sb = (const uint4*)(a16 + (size_t)((Bq + b) * 2 + jh) * IMG);
        uint4* dA = (uint4*)As;
        uint4* dB = (uint4*)Bs;

        int lane = t & 63;
        int wv = t >> 6;
        int wr = wv & 1, wc = wv >> 1;
        int lm = lane & 15, lq = lane >> 4;

        f32x4 acc[4][4];
#pragma unroll
        for (int tm = 0; tm < 4; tm++)
#pragma unroll
            for (int tn = 0; tn < 4; tn++) acc[tm][tn] = 0.f;

#pragma unroll
        for (int q = 0; q < 2; q++) {
            // stage K-chunk q (h shorts [q*64, q*64+64)): 1024 uint4 per matrix
#pragma unroll
            for (int it = 0; it < 4; it++) {
                int idx = t + 256 * it;          // 0..1023
                int row = idx >> 3, cc = idx & 7;
                dA[row * 9 + cc] = sa[row * 17 + q * 8 + cc];
                int hb = (q * 8 + cc) * 8;
                uint4 ch = sb[row * 17 + q * 8 + cc];
                float4 wA = *(const float4*)(w2s + hb);
                float4 wB = *(const float4*)(w2s + hb + 4);
                uint4 o;
                o.x = mulpack(ch.x, wA.x, wA.y);
                o.y = mulpack(ch.y, wA.z, wA.w);
                o.z = mulpack(ch.z, wB.x, wB.y);
                o.w = mulpack(ch.w, wB.z, wB.w);
                dB[row * 9 + cc] = o;
            }
            __syncthreads();
#pragma unroll
            for (int ksl = 0; ksl < 2; ksl++) {
                bf16x8 af[4], bfr[4];
#pragma unroll
                for (int tm = 0; tm < 4; tm++)
                    af[tm] = *(const bf16x8*)&As[(wr * 64 + tm * 16 + lm) * 72 + ksl * 32 + lq * 8];
#pragma unroll
                for (int tn = 0; tn < 4; tn++)
                    bfr[tn] = *(const bf16x8*)&Bs[(wc * 64 + tn * 16 + lm) * 72 + ksl * 32 + lq * 8];
#pragma unroll
                for (int tm = 0; tm < 4; tm++)
#pragma unroll
                    for (int tn = 0; tn < 4; tn++)
                        acc[tm][tn] = __builtin_amdgcn_mfma_f32_16x16x32_bf16(af[tm], bfr[tn], acc[tm][tn], 0, 0, 0);
            }
            __syncthreads();
        }

        const float* wn0 = wn + ((size_t)b * PPq + p) * Sq;
        const float* wn1 = wn + ((size_t)(Bq + b) * PPq + p) * Sq;
        const float* mfp = mf + b * Sq;
        const float* mfh = mf + (size_t)Bq * Sq + b * Sq;
        size_t base = ((size_t)b * PPq + p) * Sq;
        float rn2v[4], mzh[4];
#pragma unroll
        for (int tn = 0; tn < 4; tn++) {
            int jj = j0 + wc * 64 + tn * 16 + lm;
            rn2v[tn] = wn1[jj];
            mzh[tn] = mfh[jj] > 0.5f ? 0.f : NEGB;
        }
        float cmax[4] = {NEGB, NEGB, NEGB, NEGB};
        float csum[4] = {0.f, 0.f, 0.f, 0.f};
#pragma unroll
        for (int tm = 0; tm < 4; tm++) {
            int ibase = i0 + wr * 64 + tm * 16 + lq * 4;
            float rn1v[4], mzp[4];
#pragma unroll
            for (int r2 = 0; r2 < 4; r2++) {
                rn1v[r2] = wn0[ibase + r2];
                mzp[r2] = mfp[ibase + r2] > 0.5f ? 0.f : NEGB;
            }
            float rmax[4] = {NEGB, NEGB, NEGB, NEGB};
            float rsum[4] = {0.f, 0.f, 0.f, 0.f};
#pragma unroll
            for (int tn = 0; tn < 4; tn++)
#pragma unroll
                for (int r2 = 0; r2 < 4; r2++) {
                    float v = acc[tm][tn][r2] * rn1v[r2] * rn2v[tn];
                    rmax[r2] = fmaxf(rmax[r2], v + mzh[tn]);
                    rsum[r2] += v;
                    cmax[tn] = fmaxf(cmax[tn], v + mzp[r2]);
                    csum[tn] += v;
                }
#pragma unroll
            for (int r2 = 0; r2 < 4; r2++)
#pragma unroll
                for (int o = 1; o < 16; o <<= 1) {
                    rmax[r2] = fmaxf(rmax[r2], __shfl_xor(rmax[r2], o, 64));
                    rsum[r2] += __shfl_xor(rsum[r2], o, 64);
                }
            if (lm == 0) {
#pragma unroll
                for (int r2 = 0; r2 < 4; r2++) {
                    atomicMax(rowmax + base + ibase + r2, fkey(rmax[r2]));
                    atomicAdd(rowsum + base + ibase + r2, rsum[r2]);
                }
            }
        }
#pragma unroll
        for (int tn = 0; tn < 4; tn++) {
#pragma unroll
            for (int o = 16; o < 64; o <<= 1) {
                cmax[tn] = fmaxf(cmax[tn], __shfl_xor(cmax[tn], o, 64));
                csum[tn] += __shfl_xor(csum[tn], o, 64);
            }
        }
        if (lq == 0) {
#pragma unroll
            for (int tn = 0; tn < 4; tn++) {
                int jj = j0 + wc * 64 + tn * 16 + lm;
                atomicMax(colmax + base + jj, fkey(cmax[tn]));
                atomicAdd(colsum + base + jj, csum[tn]);
            }
        }
        return;
    }

    // ---------------- exact-f32 plain cosine path (p == 20), blocks 0..63 ----------------
    float (*cbmax)[Sq] = (float (*)[Sq])As;             // 0..4 KB of As
    float (*cbsum)[Sq] = (float (*)[Sq])(As + 4096);    // 8..12 KB of As (within 18 KB)
    int b = blk >> 3, it = blk & 7;
    int lane = t & 63;
    int wid = __builtin_amdgcn_readfirstlane(t >> 6);
    int i0 = it * 32 + wid * 8;

    const float* abase2 = vmT + (size_t)b * Hq * Sq;
    const float* bbase2 = vmT + (size_t)(Bq + b) * Hq * Sq;

    float4 acc[8];
#pragma unroll
    for (int k = 0; k < 8; k++) acc[k] = make_float4(0.f, 0.f, 0.f, 0.f);

#pragma unroll 4
    for (int h = 0; h < Hq; h++) {
        float4 bq = ((const float4*)(bbase2 + h * Sq))[lane];
        const float4* ap = (const float4*)(abase2 + h * Sq + i0);
        float4 a0 = ap[0], a1 = ap[1];
        float av[8] = {a0.x, a0.y, a0.z, a0.w, a1.x, a1.y, a1.z, a1.w};
#pragma unroll
        for (int k = 0; k < 8; k++) {
            acc[k].x += av[k] * bq.x; acc[k].y += av[k] * bq.y;
            acc[k].z += av[k] * bq.z; acc[k].w += av[k] * bq.w;
        }
    }

    const float* wn0 = wn + ((size_t)b * PPq + Pq) * Sq;
    const float* wn1 = wn + ((size_t)(Bq + b) * PPq + Pq) * Sq;
    float4 rn2 = ((const float4*)wn1)[lane];
    float4 mh4 = ((const float4*)(mf + (size_t)Bq * Sq + b * Sq))[lane];
    float invLh = 1.f / fmaxf(lens[Bq + b], EPSq);

    float cmax[4] = {NEGB, NEGB, NEGB, NEGB};
    float csum[4] = {0.f, 0.f, 0.f, 0.f};
#pragma unroll
    for (int k = 0; k < 8; k++) {
        float r1 = wn0[i0 + k];
        float4 v;
        v.x = acc[k].x * r1 * rn2.x;
        v.y = acc[k].y * r1 * rn2.y;
        v.z = acc[k].z * r1 * rn2.z;
        v.w = acc[k].w * r1 * rn2.w;
        float m0 = mh4.x > 0.5f ? v.x : NEGB;
        float m1 = mh4.y > 0.5f ? v.y : NEGB;
        float m2 = mh4.z > 0.5f ? v.z : NEGB;
        float m3 = mh4.w > 0.5f ? v.w : NEGB;
        float rmax = fmaxf(fmaxf(m0, m1), fmaxf(m2, m3));
        float rs = v.x + v.y + v.z + v.w;
        for (int o = 32; o; o >>= 1) {
            rmax = fmaxf(rmax, __shfl_xor(rmax, o, 64));
            rs += __shfl_xor(rs, o, 64);
        }
        if (lane == 0) {
            float* orow = out + ((size_t)(b * Sq + i0 + k)) * Fq;
            orow[0] = rmax;
            orow[1] = rs * invLh;
        }
        float mi = mf[b * Sq + i0 + k];
        if (mi > 0.5f) {
            cmax[0] = fmaxf(cmax[0], v.x); cmax[1] = fmaxf(cmax[1], v.y);
            cmax[2] = fmaxf(cmax[2], v.z); cmax[3] = fmaxf(cmax[3], v.w);
        }
        csum[0] += v.x; csum[1] += v.y; csum[2] += v.z; csum[3] += v.w;
        ((float4*)(cosm + (size_t)(b * Sq + i0 + k) * Sq))[lane] = v;
        int jb = 4 * lane;
        cosT[((size_t)b * Sq + jb + 0) * Sq + i0 + k] = v.x;
        cosT[((size_t)b * Sq + jb + 1) * Sq + i0 + k] = v.y;
        cosT[((size_t)b * Sq + jb + 2) * Sq + i0 + k] = v.z;
        cosT[((size_t)b * Sq + jb + 3) * Sq + i0 + k] = v.w;
    }
    ((float4*)&cbmax[wid][0])[lane] = make_float4(cmax[0], cmax[1], cmax[2], cmax[3]);
    ((float4*)&cbsum[wid][0])[lane] = make_float4(csum[0], csum[1], csum[2], csum[3]);
    __syncthreads();
    {
        int j = t;
        float mx = fmaxf(fmaxf(cbmax[0][j], cbmax[1][j]), fmaxf(cbmax[2][j], cbmax[3][j]));
        float sm = cbsum[0][j] + cbsum[1][j] + cbsum[2][j] + cbsum[3][j];
        size_t cidx = ((size_t)b * PPq + Pq) * Sq + j;
        atomicMax(colmax + cidx, fkey(mx));
        atomicAdd(colsum + cidx, sm);
    }
}

// ---------------- k_att: 256 threads, 1 vB load feeds 8 r's, kh 2-split -------------------
__global__ __launch_bounds__(256) void k_att(
    const float* __restrict__ vm, const float* __restrict__ mf,
    const float* __restrict__ cosm, const float* __restrict__ cosT,
    const unsigned* __restrict__ rowmax, const float* __restrict__ rowsum,
    const unsigned* __restrict__ colmax, const float* __restrict__ colsum,
    const float* __restrict__ lens,
    float* __restrict__ out,
    float* __restrict__ attvT) {
    __shared__ float L[Sq * 8];          // [k][8 r]
    __shared__ float bm[Sq];
    __shared__ float pam[2][8][128];
    __shared__ float pax[2][8][128];
    int blk = blockIdx.x;
    int t = threadIdx.x;
    int d = blk >> 8;
    int rem = blk & 255;
    int b = rem >> 5, rt = rem & 31;
    int r0 = rt * 8;

    if (blk < Bq * PPq) {            // col fold -> dir1 rows
        int bcf = blk / PPq, pcf = blk - bcf * PPq;
        float mx = funkey(colmax[(size_t)blk * Sq + t]);
        float sm = colsum[(size_t)blk * Sq + t];
        float invLp = 1.f / fmaxf(lens[bcf], EPSq);
        float* orow = out + (size_t)Bq * Sq * Fq + (size_t)(bcf * Sq + t) * Fq;
        if (pcf < Pq) { orow[23 + pcf] = mx; orow[43 + pcf] = sm * invLp; }
        else { orow[0] = mx; orow[1] = sm * invLp; }
    } else if (blk < 2 * Bq * PPq) { // row fold -> dir0 rows (p<20; p==20 by cos path)
        int rf = blk - Bq * PPq;
        int bcf = rf / PPq, pcf = rf - bcf * PPq;
        if (pcf < Pq) {
            float mx = funkey(rowmax[(size_t)(bcf * PPq + pcf) * Sq + t]);
            float sm = rowsum[(size_t)(bcf * PPq + pcf) * Sq + t];
            float invLh = 1.f / fmaxf(lens[Bq + bcf], EPSq);
            float* orow = out + (size_t)(bcf * Sq + t) * Fq;
            orow[23 + pcf] = mx; orow[43 + pcf] = sm * invLh;
        }
    }
    bm[t] = (mf[(size_t)(1 - d) * Bq * Sq + b * Sq + t] > 0.5f) ? 0.f : NEGB;

    const float* src = (d ? cosm : cosT) + (size_t)b * Sq * Sq;
#pragma unroll
    for (int q = 0; q < 2; q++) {
        int F = t + 256 * q;
        int k = F >> 1, c = F & 1;
        float4 v4 = *(const float4*)(src + (size_t)k * Sq + r0 + c * 4);
        *(float4*)(L + k * 8 + c * 4) = v4;
    }
    __syncthreads();

    int h = t & 127, kh = t >> 7;
    const float* vB = vm + (size_t)(1 - d) * Bq * Sq * Hq + (size_t)b * Sq * Hq + h;
    bool hv = (h < Hq);
    float am[8], ax[8];
#pragma unroll
    for (int r = 0; r < 8; r++) { am[r] = 0.f; ax[r] = NEGB; }
    int k0 = kh * 128;
#pragma unroll 16
    for (int kk = 0; kk < 128; kk++) {
        int k = k0 + kk;
        float v = hv ? vB[(size_t)k * Hq] : 0.f;
        float4 w0 = *(const float4*)(L + k * 8);
        float4 w1 = *(const float4*)(L + k * 8 + 4);
        float bk = bm[k];
        float wv[8] = {w0.x, w0.y, w0.z, w0.w, w1.x, w1.y, w1.z, w1.w};
#pragma unroll
        for (int r = 0; r < 8; r++) {
            float pr = wv[r] * v;
            am[r] += pr;
            ax[r] = fmaxf(ax[r], pr + bk);
        }
    }
#pragma unroll
    for (int r = 0; r < 8; r++) { pam[kh][r][h] = am[r]; pax[kh][r][h] = ax[r]; }
    __syncthreads();
    if (t < Hq) {
        float4 m0, m1, x0, x1;
        m0.x = pam[0][0][t] + pam[1][0][t]; x0.x = fmaxf(pax[0][0][t], pax[1][0][t]);
        m0.y = pam[0][1][t] + pam[1][1][t]; x0.y = fmaxf(pax[0][1][t], pax[1][1][t]);
        m0.z = pam[0][2][t] + pam[1][2][t]; x0.z = fmaxf(pax[0][2][t], pax[1][2][t]);
        m0.w = pam[0][3][t] + pam[1][3][t]; x0.w = fmaxf(pax[0][3][t], pax[1][3][t]);
        m1.x = pam[0][4][t] + pam[1][4][t]; x1.x = fmaxf(pax[0][4][t], pax[1][4][t]);
        m1.y = pam[0][5][t] + pam[1][5][t]; x1.y = fmaxf(pax[0][5][t], pax[1][5][t]);
        m1.z = pam[0][6][t] + pam[1][6][t]; x1.z = fmaxf(pax[0][6][t], pax[1][6][t]);
        m1.w = pam[0][7][t] + pam[1][7][t]; x1.w = fmaxf(pax[0][7][t], pax[1][7][t]);
        float* om = attvT + (((size_t)(d * 2 + 0) * Bq + b) * Hq + t) * Sq + r0;
        float* ox = attvT + (((size_t)(d * 2 + 1) * Bq + b) * Hq + t) * Sq + r0;
        *(float4*)om = m0; *(float4*)(om + 4) = m1;
        *(float4*)ox = x0; *(float4*)(ox + 4) = x1;
    }
}

// ---------------- k_final: p-sliced — grid 960 = 3m*2dir*8b*2sc*10ps, 128 thr -------------
__global__ __launch_bounds__(128) void k_final(
    const float* __restrict__ vm, const float* __restrict__ vmT,
    const int* __restrict__ lasts, const float* __restrict__ attvT,
    const float* __restrict__ w_full, const float* __restrict__ w_att,
    const float* __restrict__ w_maxatt,
    float* __restrict__ out) {
    __shared__ float w2s[Hq * 2];    // [h][2] slice of w^2
    __shared__ float v2u[Hq];
    int blk = blockIdx.x;
    int m = blk / 320;               // 2dir * 8b * 2sc * 10ps = 320
    int rem = blk - m * 320;
    int dir = rem / 160; rem -= dir * 160;
    int b = rem / 20;    rem -= b * 20;
    int sc = rem / 10;
    int ps = rem - sc * 10;
    int t = threadIdx.x;
    const float* W = (m == 0) ? w_full : (m == 1) ? w_att : w_maxatt;
    for (int idx = t; idx < 2 * Hq; idx += 128) {
        int pp = idx / Hq, h = idx - pp * Hq;
        float w = W[(ps * 2 + pp) * Hq + h];
        w2s[h * 2 + pp] = w * w;
    }
    if (m == 0 && t < Hq) {
        int lastO = dir ? lasts[b] : lasts[Bq + b];
        v2u[t] = vm[(size_t)(1 - dir) * Bq * Sq * Hq + ((size_t)b * Sq + lastO) * Hq + t];
    }
    __syncthreads();

    int s = sc * 128 + t;
    const float* v1T = vmT + (size_t)(dir * Bq + b) * Hq * Sq + s;
    const float* v2T = attvT + ((size_t)(dir * 2 + (m == 2 ? 1 : 0)) * Bq + b) * Hq * Sq + s;

    float d0 = 0.f, a0 = 0.f, b0 = 0.f;
    float d1 = 0.f, a1 = 0.f, b1 = 0.f;
    float pd = 0.f, p1 = 0.f, p2 = 0.f;
#pragma unroll 4
    for (int h = 0; h < Hq; h++) {
        float v1 = v1T[h * Sq];
        float v2 = (m == 0) ? v2u[h] : v2T[h * Sq];
        float e1 = v1 * v2, e2 = v1 * v1, e3 = v2 * v2;
        float w0 = w2s[h * 2], w1 = w2s[h * 2 + 1];
        d0 += w0 * e1; a0 += w0 * e2; b0 += w0 * e3;
        d1 += w1 * e1; a1 += w1 * e2; b1 += w1 * e3;
        if (ps == 0) { pd += e1; p1 += e2; p2 += e3; }
    }
    int fbase = (m == 0) ? 2 : (m == 1) ? 63 : 84;
    float* orow = out + (size_t)dir * Bq * Sq * Fq + ((size_t)b * Sq + s) * Fq;
    if (ps == 0)
        orow[fbase] = pd / (fmaxf(sqrtf(p1), EPSq) * fmaxf(sqrtf(p2), EPSq));
    orow[fbase + 1 + ps * 2]     = d0 / (fmaxf(sqrtf(a0), EPSq) * fmaxf(sqrtf(b0), EPSq));
    orow[fbase + 1 + ps * 2 + 1] = d1 / (fmaxf(sqrtf(a1), EPSq) * fmaxf(sqrtf(b1), EPSq));
}

extern "C" void kernel_launch(void* const* d_in, const int* in_sizes, int n_in,
                              void* d_out, int out_size, void* d_ws, size_t ws_size,
                              hipStream_t stream) {
    (void)in_sizes; (void)n_in; (void)out_size; (void)ws_size;
    const float* ctx_p    = (const float*)d_in[0];
    const int*   mask_p   = (const int*)d_in[1];
    const float* ctx_h    = (const float*)d_in[2];
    const int*   mask_h   = (const int*)d_in[3];
    const float* w_full   = (const float*)d_in[4];
    const float* w_maxpool= (const float*)d_in[5];
    const float* w_att    = (const float*)d_in[6];
    const float* w_maxatt = (const float*)d_in[7];
    float* out = (float*)d_out;
    float* ws = (float*)d_ws;

    const size_t BSH = (size_t)Bq * Sq * Hq;
    const size_t BS  = (size_t)Bq * Sq;
    const size_t BSS = (size_t)Bq * Sq * Sq;
    const size_t BPS = (size_t)Bq * PPq * Sq;

    float* vm     = ws;               ws += 2 * BSH;
    float* vmT    = ws;               ws += 2 * BSH;
    unsigned short* a16 = (unsigned short*)ws;  ws += 2 * Bq * IMG / 2 * 2;  // 2*8*2*IMG shorts
    float* mf     = ws;               ws += 2 * BS;
    float* wn     = ws;               ws += 2 * BPS;
    float* cosm   = ws;               ws += BSS;
    float* cosT   = ws;               ws += BSS;
    unsigned* rowmax = (unsigned*)ws; ws += BPS;
    float* rowsum = ws;               ws += BPS;
    unsigned* colmax = (unsigned*)ws; ws += BPS;
    float* colsum = ws;               ws += BPS;   // row/col stat bufs contiguous (one zero pass)
    float* attvT  = ws;               ws += 4 * BSH;
    float* lens   = ws;               ws += 16;
    int*   lasts  = (int*)ws;         ws += 16;

    k_prep<<<64, 256, 0, stream>>>(ctx_p, mask_p, ctx_h, mask_h, w_maxpool,
                                   vm, vmT, mf, wn, a16, lens, lasts, rowmax);
    k_pw<<<704, 256, 0, stream>>>(a16, vmT, wn, mf, w_maxpool, lens,
                                  out, cosm, cosT, rowmax, rowsum, colmax, colsum);
    k_att<<<512, 256, 0, stream>>>(vm, mf, cosm, cosT, rowmax, rowsum, colmax, colsum,
                                   lens, out, attvT);
    k_final<<<960, 128, 0, stream>>>(vm, vmT, lasts, attvT, w_full, w_att, w_maxatt, out);
}